// Round 9
// baseline (485.410 us; speedup 1.0000x reference)
//
#include <hip/hip_runtime.h>

typedef __attribute__((ext_vector_type(8))) short s16x8;
typedef __attribute__((ext_vector_type(4))) float f32x4;

#define DEV static __device__ __forceinline__

DEV float b2f(unsigned short u){
  unsigned int i = ((unsigned int)u) << 16;
  float f; __builtin_memcpy(&f, &i, 4); return f;
}
DEV unsigned short f2b(float f){
  unsigned int i; __builtin_memcpy(&i, &f, 4);
  i = i + 0x7fffu + ((i >> 16) & 1u);
  return (unsigned short)(i >> 16);
}
DEV f32x4 mfma16(s16x8 a, s16x8 b, f32x4 c){
  return __builtin_amdgcn_mfma_f32_16x16x32_bf16(a, b, c, 0, 0, 0);
}
// load 8 consecutive f32 (32B-aligned) -> bf16 A/B fragment
DEV s16x8 ld8f(const float* p){
  const float4* q4 = (const float4*)p;
  float4 a = q4[0], b = q4[1];
  s16x8 r;
  r[0]=(short)f2b(a.x); r[1]=(short)f2b(a.y); r[2]=(short)f2b(a.z); r[3]=(short)f2b(a.w);
  r[4]=(short)f2b(b.x); r[5]=(short)f2b(b.y); r[6]=(short)f2b(b.z); r[7]=(short)f2b(b.w);
  return r;
}

// DPP-based 16-lane all-reduce sum
template<int C> DEV float dpp_addstep(float x){
  int y = __builtin_amdgcn_update_dpp(0, __builtin_bit_cast(int, x), C, 0xF, 0xF, true);
  return x + __builtin_bit_cast(float, y);
}
DEV float rsum16(float v){
  v = dpp_addstep<0xB1>(v);   // quad_perm xor1
  v = dpp_addstep<0x4E>(v);   // quad_perm xor2
  v = dpp_addstep<0x141>(v);  // row_half_mirror
  v = dpp_addstep<0x140>(v);  // row_mirror
  return v;
}

// Software grid barrier (sense-reversing, device-scope atomics, bounded spin).
// Requires all blocks co-resident: grid 512 <= capacity 1024 (launch_bounds
// (256,4): VGPR<=128 -> 4 blk/CU; LDS 40.4KB -> 4 blk/CU). Writer-release
// (__threadfence = L2 writeback) before arrive; acquire fence after.
DEV void gridbar(unsigned int* bar, unsigned int nblk){
  __syncthreads();
  if (threadIdx.x == 0){
    __threadfence();
    unsigned int g = __hip_atomic_load(&bar[1], __ATOMIC_RELAXED, __HIP_MEMORY_SCOPE_AGENT);
    unsigned int old = __hip_atomic_fetch_add(&bar[0], 1u, __ATOMIC_ACQ_REL, __HIP_MEMORY_SCOPE_AGENT);
    if (old == nblk - 1u){
      __hip_atomic_store(&bar[0], 0u, __ATOMIC_RELAXED, __HIP_MEMORY_SCOPE_AGENT);
      __hip_atomic_store(&bar[1], g + 1u, __ATOMIC_RELEASE, __HIP_MEMORY_SCOPE_AGENT);
    } else {
      int tries = 0;
      while (__hip_atomic_load(&bar[1], __ATOMIC_ACQUIRE, __HIP_MEMORY_SCOPE_AGENT) == g){
        if (++tries > (1 << 24)) break;   // failsafe: never hang the harness
      }
    }
    __threadfence();
  }
  __syncthreads();
}

// ---------------------------------------------------------------------------
// K0: one-shot pack of ALL weights -> bf16 + zero the grid-barrier state.
// wall layout (elements): wih@0 whh@12288 w1@24576 w2@32768 wq@40960.
// ---------------------------------------------------------------------------
__global__ __launch_bounds__(256) void k_wpack(
    const float* __restrict__ Wk, const float* __restrict__ Wv,
    const float* __restrict__ wih, const float* __restrict__ whh,
    const float* __restrict__ w1, const float* __restrict__ w2,
    const float* __restrict__ Wq,
    unsigned short* __restrict__ wkb, unsigned short* __restrict__ wvb,
    unsigned short* __restrict__ wall,
    unsigned int* __restrict__ bar)
{
  if (blockIdx.x == 0 && threadIdx.x == 0){ bar[0] = 0u; bar[1] = 0u; }
  int t = blockIdx.x * 256 + threadIdx.x;
  int off = t * 4;
  const float* src; unsigned short* dst;
  if      (off <  8192){ src = Wk  + off;         dst = wkb  + off; }
  else if (off < 16384){ src = Wv  + off -  8192; dst = wvb  + off - 8192; }
  else if (off < 28672){ src = wih + off - 16384; dst = wall + off - 16384; }
  else if (off < 40960){ src = whh + off - 28672; dst = wall + off - 16384; }
  else if (off < 49152){ src = w1  + off - 40960; dst = wall + off - 16384; }
  else if (off < 57344){ src = w2  + off - 49152; dst = wall + off - 16384; }
  else                 { src = Wq  + off - 57344; dst = wall + off - 16384; }
  float4 v = *(const float4*)src;
  ushort4 o;
  o.x = f2b(v.x); o.y = f2b(v.y); o.z = f2b(v.z); o.w = f2b(v.w);
  *(ushort4*)dst = o;
}

// ---------------------------------------------------------------------------
// K1: LN(x) -> k (plain [b][n][h] bf16), v^T ([b][h][n] bf16). UNCHANGED
// (41.7us, FETCH 33MB / WRITE 33MB verified).
// INVARIANT: each wave covers TWO adjacent 16-col vt tiles (64B/row from one
// wave back-to-back) -- this is what lets L2 merge the sub-line stores.
// ---------------------------------------------------------------------------
__global__ __launch_bounds__(256, 4) void k_lnkv5(
    const float* __restrict__ x,
    const unsigned short* __restrict__ wkb,
    const unsigned short* __restrict__ wvb,
    const float* __restrict__ lg,
    const float* __restrict__ lb,
    unsigned short* __restrict__ kg,
    unsigned short* __restrict__ vt,
    const float* __restrict__ noise,
    const float* __restrict__ mu,
    const float* __restrict__ lsg,
    const float* __restrict__ gsl,
    const float* __restrict__ bsl,
    const float* __restrict__ Wq,
    float* __restrict__ slots,
    unsigned short* __restrict__ qws)
{
  __shared__ __align__(16) unsigned int xs[128 * 68];
  const int tid = threadIdx.x;
  const int w = tid >> 6, ln = tid & 63;
  const int m16 = ln & 15, q = ln >> 4;

  if (blockIdx.x >= 1024){
    // ---------------- slot-init path (16 tail blocks) ----------------
    unsigned short* st = (unsigned short*)xs;
    float (*redS)[4] = (float(*)[4])((char*)xs + 2304);
    float (*redQ)[4] = (float(*)[4])((char*)xs + 2560);
    const int bi = blockIdx.x - 1024;
    const int r0 = bi * 16;
    const int cw = w*16 + m16;

    float sl[4], s1[4], s2[4];
    #pragma unroll
    for (int rr = 0; rr < 4; ++rr){
      int row = r0 + q*4 + rr;
      int k = row & 7;
      float v = mu[k*64 + cw] + (log1pf(expf(lsg[k*64 + cw])) + 1e-5f) * noise[row*64 + cw];
      sl[rr] = v;
      slots[row*64 + cw] = v;
      s1[rr] = rsum16(v);
      s2[rr] = rsum16(v*v);
    }
    if (m16 == 0){
      #pragma unroll
      for (int rr = 0; rr < 4; ++rr){ redS[q*4+rr][w] = s1[rr]; redQ[q*4+rr][w] = s2[rr]; }
    }
    __syncthreads();
    {
      const float gs = gsl[cw], bs = bsl[cw];
      #pragma unroll
      for (int rr = 0; rr < 4; ++rr){
        f32x4 aS = *(const f32x4*)redS[q*4+rr];
        f32x4 aQ = *(const f32x4*)redQ[q*4+rr];
        float tS = aS[0]+aS[1]+aS[2]+aS[3];
        float tQ = aQ[0]+aQ[1]+aQ[2]+aQ[3];
        float mean = tS*(1.f/64.f);
        float var  = tQ*(1.f/64.f) - mean*mean;
        float rs = rsqrtf(var + 1e-5f);
        float sq = (sl[rr] - mean)*rs*gs + bs;
        st[(q*4+rr)*72 + cw] = f2b(sq);
      }
    }
    __syncthreads();
    {
      f32x4 acc = {0,0,0,0};
      #pragma unroll
      for (int ks = 0; ks < 2; ++ks){
        s16x8 a = *(const s16x8*)(st + m16*72 + ks*32 + q*8);
        acc = mfma16(a, ld8f(Wq + cw*64 + ks*32 + q*8), acc);
      }
      #pragma unroll
      for (int rr = 0; rr < 4; ++rr){
        int row = r0 + q*4 + rr;
        int bb_ = row >> 3, kk = row & 7;
        qws[(bb_*16 + kk)*64 + cw] = f2b(acc[rr] * 0.125f);
      }
      int b0 = bi * 2;
      ((unsigned int*)(qws + (b0*16 + 8)*64))[tid] = 0u;
      ((unsigned int*)(qws + ((b0+1)*16 + 8)*64))[tid] = 0u;
    }
    return;
  }

  // ---------------- LN + KV path (1024 blocks, 128 rows each) -------------
  const int b = blockIdx.x >> 5;
  const int nbase = (blockIdx.x & 31) << 7;
  const long rowg0 = (long)b * 4096 + nbase;

  {
    const int c = m16;
    const float4 gA = *(const float4*)(lg + c*4);
    const float4 gB = *(const float4*)(lg + 64 + c*4);
    const float4 bA = *(const float4*)(lb + c*4);
    const float4 bB = *(const float4*)(lb + 64 + c*4);
    const float* base = x + (rowg0 + w*32 + q)*128;

    float4 va[2], vb[2];
    va[0] = *(const float4*)(base + c*4);
    vb[0] = *(const float4*)(base + 64 + c*4);
    #pragma unroll
    for (int p = 0; p < 8; ++p){
      const int cur = p & 1, nxt = cur ^ 1;
      if (p < 7){
        va[nxt] = *(const float4*)(base + (p+1)*512 + c*4);
        vb[nxt] = *(const float4*)(base + (p+1)*512 + 64 + c*4);
      }
      float4 u = va[cur], t = vb[cur];
      float s1 = (u.x + u.y) + (u.z + u.w) + (t.x + t.y) + (t.z + t.w);
      float s2 = (u.x*u.x + u.y*u.y) + (u.z*u.z + u.w*u.w)
               + (t.x*t.x + t.y*t.y) + (t.z*t.z + t.w*t.w);
      s1 = rsum16(s1);
      s2 = rsum16(s2);
      float mean = s1 * (1.f/128.f);
      float var  = s2 * (1.f/128.f) - mean*mean;
      float rs = rsqrtf(var + 1e-5f);
      float y0 = (u.x - mean)*rs*gA.x + bA.x;
      float y1 = (u.y - mean)*rs*gA.y + bA.y;
      float y2 = (u.z - mean)*rs*gA.z + bA.z;
      float y3 = (u.w - mean)*rs*gA.w + bA.w;
      float y4 = (t.x - mean)*rs*gB.x + bB.x;
      float y5 = (t.y - mean)*rs*gB.y + bB.y;
      float y6 = (t.z - mean)*rs*gB.z + bB.z;
      float y7 = (t.w - mean)*rs*gB.w + bB.w;
      uint2 pkA, pkB;
      pkA.x = (unsigned int)f2b(y0) | ((unsigned int)f2b(y1) << 16);
      pkA.y = (unsigned int)f2b(y2) | ((unsigned int)f2b(y3) << 16);
      pkB.x = (unsigned int)f2b(y4) | ((unsigned int)f2b(y5) << 16);
      pkB.y = (unsigned int)f2b(y6) | ((unsigned int)f2b(y7) << 16);
      const int r = w*32 + p*4 + q;
      *(uint2*)&xs[r*68 + c*2] = pkA;
      *(uint2*)&xs[r*68 + 32 + c*2] = pkB;
    }
  }

  s16x8 bw[4][4];
  #pragma unroll
  for (int t = 0; t < 4; ++t)
    #pragma unroll
    for (int kb = 0; kb < 4; ++kb)
      bw[kb][t] = *(const s16x8*)(wkb + (t*16 + m16)*128 + kb*32 + q*8);

  __syncthreads();

  const f32x4 zf = {0.f, 0.f, 0.f, 0.f};

  #pragma unroll
  for (int mi = 0; mi < 2; ++mi){
    int n0 = (w*2 + mi) * 16;
    f32x4 acc[4];
    #pragma unroll
    for (int t = 0; t < 4; ++t) acc[t] = zf;
    #pragma unroll
    for (int kb = 0; kb < 4; ++kb){
      s16x8 af = *(const s16x8*)((const unsigned short*)(xs + (n0 + m16)*68) + kb*32 + q*8);
      #pragma unroll
      for (int t = 0; t < 4; ++t)
        acc[t] = mfma16(af, bw[kb][t], acc[t]);
    }
    #pragma unroll
    for (int t = 0; t < 4; ++t){
      int h = t*16 + m16;
      #pragma unroll
      for (int rr = 0; rr < 4; ++rr){
        long n = rowg0 + n0 + q*4 + rr;
        kg[n*64 + h] = f2b(acc[t][rr]);
      }
    }
  }

  #pragma unroll
  for (int t = 0; t < 4; ++t)
    #pragma unroll
    for (int kb = 0; kb < 4; ++kb)
      bw[kb][t] = *(const s16x8*)(wvb + (t*16 + m16)*128 + kb*32 + q*8);

  #pragma unroll
  for (int mi = 0; mi < 2; ++mi){
    int n0 = (w*2 + mi) * 16;
    f32x4 acc[4];
    #pragma unroll
    for (int t = 0; t < 4; ++t) acc[t] = zf;
    #pragma unroll
    for (int kb = 0; kb < 4; ++kb){
      s16x8 af = *(const s16x8*)((const unsigned short*)(xs + (n0 + m16)*68) + kb*32 + q*8);
      #pragma unroll
      for (int t = 0; t < 4; ++t)
        acc[t] = mfma16(af, bw[kb][t], acc[t]);
    }
    #pragma unroll
    for (int t = 0; t < 4; ++t){
      int h = t*16 + m16;
      unsigned int p0 = (unsigned int)f2b(acc[t][0]) | ((unsigned int)f2b(acc[t][1]) << 16);
      unsigned int p1 = (unsigned int)f2b(acc[t][2]) | ((unsigned int)f2b(acc[t][3]) << 16);
      uint2 pv; pv.x = p0; pv.y = p1;
      long off = ((long)b*64 + h)*4096 + nbase + n0 + q*4;
      *(uint2*)(vt + off) = pv;
    }
  }
}

// ---------------------------------------------------------------------------
// K2 (round-13): persistent NORMAL-launch kernel: 3x [GRU prologue + attn]
// with software grid barrier, + final GRU tail (blocks 0-15).
// 512 blocks x 256 thr; launch_bounds(256,4) => VGPR<=128 => 4 blk/CU
// capacity (1024) = 2x the grid -> co-residency guaranteed. 3-way U/S &
// slots rotation => every cross-XCD read is FIRST-TOUCH (no re-read of a
// rewritten buffer anywhere), so correctness needs only writer-side
// release + reader first-touch, both provided by gridbar's fences.
// Per-iteration body is bit-identical to the verified round-7 k_attn3.
// ---------------------------------------------------------------------------
__global__ __launch_bounds__(256, 4) void k_iter(
    const unsigned short* __restrict__ kg,
    const unsigned short* __restrict__ vt,
    const unsigned short* __restrict__ qws,
    const unsigned short* __restrict__ wall,
    const float* __restrict__ bih, const float* __restrict__ bhh,
    const float* __restrict__ b1p, const float* __restrict__ b2p,
    const float* __restrict__ gmlp, const float* __restrict__ bmlp,
    const float* __restrict__ gsl, const float* __restrict__ bsl,
    float* __restrict__ U0, float* __restrict__ U1, float* __restrict__ U2,
    float* __restrict__ S0, float* __restrict__ S1, float* __restrict__ S2,
    float* __restrict__ slotsA, float* __restrict__ slotsB,
    float* __restrict__ slotsC,
    float* __restrict__ outp,
    unsigned int* __restrict__ bar)
{
  __shared__ float sc[256*17];
  __shared__ unsigned short aT[16*264];
  __shared__ unsigned short ut[16*72], ht[16*72], st[16*72], hid[16*136];
  __shared__ unsigned short qloc[16*72];
  __shared__ __align__(16) float redS[16][4];
  __shared__ __align__(16) float redQ[16][4];
  __shared__ __align__(16) float redS2[16][4];
  __shared__ __align__(16) float redQ2[16][4];

  const int tid = threadIdx.x;
  const int w = tid >> 6, ln = tid & 63;
  const int m16 = ln & 15, q = ln >> 4;
  const int b = blockIdx.x >> 4;
  const int tile = blockIdx.x & 15;
  const int nbase = tile << 8;
  const int cw = w*16 + m16;

  const unsigned short* wihb = wall;
  const unsigned short* whhb = wall + 12288;
  const unsigned short* w1b  = wall + 24576;
  const unsigned short* w2b  = wall + 32768;
  const unsigned short* wqb  = wall + 40960;

  // one-time pad zeroing (pad rows never rewritten)
  for (int i = tid; i < 8*264; i += 256) aT[8*264 + i] = 0;
  if (tid < 128){
    int row = 8 + (tid >> 4), c = (tid & 15)*4;
    ushort4 z4 = {0,0,0,0};
    *(ushort4*)&qloc[row*72 + c] = z4;
  }

  for (int it = 0; it < 3; ++it){
    const float* Up_in  = (it == 1) ? U0 : U1;
    const float* Sp_in  = (it == 1) ? S0 : S1;
    float*       Up_out = (it == 0) ? U0 : ((it == 1) ? U1 : U2);
    float*       Sp_out = (it == 0) ? S0 : ((it == 1) ? S1 : S2);
    const float* slin   = (it == 1) ? slotsA : slotsB;
    float*       slout  = (it == 1) ? slotsB : slotsC;

    if (it == 0){
      if (tid < 128){
        int row = tid >> 4, c = (tid & 15)*4;
        *(ushort4*)&qloc[row*72 + c] = *(const ushort4*)(qws + (b*16 + row)*64 + c);
      }
    } else {
      // ---- redundant GRU+LN+MLP+LN_sl+q for batch pair (b&~1, b|1) ----
      const int r0 = (b >> 1) * 16;

      #pragma unroll
      for (int p = 0; p < 4; ++p){
        int row = p*4 + w;
        int g = r0 + row;
        int bb = g >> 3, sl = g & 7;
        const float* up  = Up_in + ((bb*16)*8 + sl)*64 + ln;
        const float* spp = Sp_in + (bb*16)*8 + sl;
        float usum = 0.f, ssum = 0.f;
        #pragma unroll
        for (int t = 0; t < 16; ++t){
          usum += up[t*512];
          ssum += spp[t*8];
        }
        ut[row*72 + ln] = f2b(usum / ssum);
        ht[row*72 + ln] = f2b(slin[g*64 + ln]);
      }
      __syncthreads();

      f32x4 axr = {0,0,0,0}, axz = {0,0,0,0}, axn = {0,0,0,0};
      f32x4 ahr = {0,0,0,0}, ahz = {0,0,0,0}, ahn = {0,0,0,0};
      #pragma unroll
      for (int ks = 0; ks < 2; ++ks){
        s16x8 au = *(const s16x8*)(ut + m16*72 + ks*32 + q*8);
        s16x8 ah = *(const s16x8*)(ht + m16*72 + ks*32 + q*8);
        axr = mfma16(au, *(const s16x8*)(wihb + (      cw)*64 + ks*32 + q*8), axr);
        axz = mfma16(au, *(const s16x8*)(wihb + ( 64 + cw)*64 + ks*32 + q*8), axz);
        axn = mfma16(au, *(const s16x8*)(wihb + (128 + cw)*64 + ks*32 + q*8), axn);
        ahr = mfma16(ah, *(const s16x8*)(whhb + (      cw)*64 + ks*32 + q*8), ahr);
        ahz = mfma16(ah, *(const s16x8*)(whhb + ( 64 + cw)*64 + ks*32 + q*8), ahz);
        ahn = mfma16(ah, *(const s16x8*)(whhb + (128 + cw)*64 + ks*32 + q*8), ahn);
      }
      const float bxr = bih[cw], bxz = bih[64+cw], bxn = bih[128+cw];
      const float bhr = bhh[cw], bhz = bhh[64+cw], bhn = bhh[128+cw];
      float sp[4];
      #pragma unroll
      for (int rr = 0; rr < 4; ++rr){
        float xr = axr[rr] + bxr, xz = axz[rr] + bxz, xnv = axn[rr] + bxn;
        float hr = ahr[rr] + bhr, hz = ahz[rr] + bhz, hn = ahn[rr] + bhn;
        float rg = 1.f / (1.f + expf(-(xr + hr)));
        float zg = 1.f / (1.f + expf(-(xz + hz)));
        float ng = tanhf(xnv + rg*hn);
        float hv = b2f(ht[(q*4 + rr)*72 + cw]);
        sp[rr] = (1.f - zg)*ng + zg*hv;
      }

      float s1[4], s2[4];
      #pragma unroll
      for (int rr = 0; rr < 4; ++rr){
        s1[rr] = rsum16(sp[rr]);
        s2[rr] = rsum16(sp[rr]*sp[rr]);
      }
      if (m16 == 0){
        #pragma unroll
        for (int rr = 0; rr < 4; ++rr){ redS[q*4+rr][w] = s1[rr]; redQ[q*4+rr][w] = s2[rr]; }
      }
      __syncthreads();
      float sl_[4];
      {
        const float gm = gmlp[cw], bm = bmlp[cw];
        #pragma unroll
        for (int rr = 0; rr < 4; ++rr){
          f32x4 aS = *(const f32x4*)redS[q*4+rr];
          f32x4 aQ = *(const f32x4*)redQ[q*4+rr];
          float tS = aS[0]+aS[1]+aS[2]+aS[3];
          float tQ = aQ[0]+aQ[1]+aQ[2]+aQ[3];
          float mean = tS*(1.f/64.f);
          float var  = tQ*(1.f/64.f) - mean*mean;
          float rs = rsqrtf(var + 1e-5f);
          sl_[rr] = (sp[rr] - mean)*rs*gm + bm;
          st[(q*4+rr)*72 + cw] = f2b(sl_[rr]);
        }
      }
      __syncthreads();

      // mlp1 (64->128) + relu
      #pragma unroll
      for (int t2 = 0; t2 < 2; ++t2){
        int nt = w*2 + t2;
        int col = nt*16 + m16;
        f32x4 acc = {0,0,0,0};
        #pragma unroll
        for (int ks = 0; ks < 2; ++ks){
          s16x8 a = *(const s16x8*)(st + m16*72 + ks*32 + q*8);
          acc = mfma16(a, *(const s16x8*)(w1b + col*64 + ks*32 + q*8), acc);
        }
        float bb = b1p[col];
        #pragma unroll
        for (int rr = 0; rr < 4; ++rr)
          hid[(q*4+rr)*136 + col] = f2b(fmaxf(acc[rr] + bb, 0.f));
      }
      __syncthreads();

      // mlp2 (128->64) + residual
      float snew[4];
      {
        f32x4 acc = {0,0,0,0};
        #pragma unroll
        for (int ks = 0; ks < 4; ++ks){
          s16x8 a = *(const s16x8*)(hid + m16*136 + ks*32 + q*8);
          acc = mfma16(a, *(const s16x8*)(w2b + cw*128 + ks*32 + q*8), acc);
        }
        float bb = b2p[cw];
        #pragma unroll
        for (int rr = 0; rr < 4; ++rr){
          snew[rr] = sl_[rr] + acc[rr] + bb;
          if ((blockIdx.x & 31) == 0)
            slout[(r0 + q*4 + rr)*64 + cw] = snew[rr];   // one gate block per pair
        }
      }

      // LN_sl(snew) -> q into qloc
      #pragma unroll
      for (int rr = 0; rr < 4; ++rr){
        s1[rr] = rsum16(snew[rr]);
        s2[rr] = rsum16(snew[rr]*snew[rr]);
      }
      if (m16 == 0){
        #pragma unroll
        for (int rr = 0; rr < 4; ++rr){ redS2[q*4+rr][w] = s1[rr]; redQ2[q*4+rr][w] = s2[rr]; }
      }
      __syncthreads();
      {
        const float gs = gsl[cw], bs = bsl[cw];
        #pragma unroll
        for (int rr = 0; rr < 4; ++rr){
          f32x4 aS = *(const f32x4*)redS2[q*4+rr];
          f32x4 aQ = *(const f32x4*)redQ2[q*4+rr];
          float tS = aS[0]+aS[1]+aS[2]+aS[3];
          float tQ = aQ[0]+aQ[1]+aQ[2]+aQ[3];
          float mean = tS*(1.f/64.f);
          float var  = tQ*(1.f/64.f) - mean*mean;
          float rs = rsqrtf(var + 1e-5f);
          float sq = (snew[rr] - mean)*rs*gs + bs;
          st[(q*4+rr)*72 + cw] = f2b(sq);
        }
      }
      __syncthreads();
      {
        f32x4 acc = {0,0,0,0};
        #pragma unroll
        for (int ks = 0; ks < 2; ++ks){
          s16x8 a = *(const s16x8*)(st + m16*72 + ks*32 + q*8);
          acc = mfma16(a, *(const s16x8*)(wqb + cw*64 + ks*32 + q*8), acc);
        }
        #pragma unroll
        for (int rr = 0; rr < 4; ++rr){
          int rloc = q*4 + rr;
          if ((rloc >> 3) == (b & 1))
            qloc[(rloc & 7)*72 + cw] = f2b(acc[rr] * 0.125f);
        }
      }
    }
    __syncthreads();

    // ---- attention ----
    s16x8 bq[2];
    #pragma unroll
    for (int ks = 0; ks < 2; ++ks)
      bq[ks] = *(const s16x8*)(qloc + m16*72 + ks*32 + q*8);

    #pragma unroll
    for (int mi = 0; mi < 4; ++mi){
      int n0 = (w*4 + mi)*16;
      f32x4 acc = {0.f, 0.f, 0.f, 0.f};
      #pragma unroll
      for (int ks = 0; ks < 2; ++ks){
        s16x8 af = *(const s16x8*)(kg + ((long)b*4096 + nbase + n0 + m16)*64 + ks*32 + q*8);
        acc = mfma16(af, bq[ks], acc);
      }
      #pragma unroll
      for (int rr = 0; rr < 4; ++rr)
        sc[(n0 + q*4 + rr)*17 + m16] = acc[rr];
    }
    __syncthreads();

    {
      int r = tid;
      float a8[8];
      float mx = -1e30f;
      #pragma unroll
      for (int j = 0; j < 8; ++j){ a8[j] = sc[r*17 + j]; mx = fmaxf(mx, a8[j]); }
      float ssum = 0.f;
      #pragma unroll
      for (int j = 0; j < 8; ++j){ a8[j] = expf(a8[j] - mx); ssum += a8[j]; }
      float inv = 1.f/ssum;
      #pragma unroll
      for (int j = 0; j < 8; ++j)
        aT[j*264 + r] = f2b(a8[j]*inv + 1e-8f);
    }
    __syncthreads();

    {  // S tile-partials
      int j = tid >> 5, c = tid & 31;
      float p = 0.f;
      #pragma unroll
      for (int i = 0; i < 8; ++i) p += b2f(aT[j*264 + c + 32*i]);
      p = rsum16(p);
      p += __shfl_xor(p, 16);
      if ((tid & 31) == 0) Sp_out[(b*16 + tile)*8 + j] = p;
    }

    {  // U tile-partials
      f32x4 acc = {0.f, 0.f, 0.f, 0.f};
      #pragma unroll
      for (int ks = 0; ks < 8; ++ks){
        s16x8 af = *(const s16x8*)(aT + m16*264 + ks*32 + q*8);
        s16x8 bf = *(const s16x8*)(vt + ((long)b*64 + w*16 + m16)*4096 + nbase + ks*32 + q*8);
        acc = mfma16(af, bf, acc);
      }
      float* ub = Up_out + ((b*16 + tile)*8)*64 + w*16 + m16;
      #pragma unroll
      for (int rr = 0; rr < 4; ++rr){
        int slot = q*4 + rr;
        if (slot < 8)
          ub[slot*64] = acc[rr];
      }
    }

    gridbar(bar, 512u);
  }

  // ---- final GRU + LN_mlp + MLP(+residual) -> outp (blocks 0..15) ----
  if (blockIdx.x >= 16) return;
  {
    const int r0 = blockIdx.x * 16;

    #pragma unroll
    for (int p = 0; p < 4; ++p){
      int row = p*4 + w;
      int g = r0 + row;
      int bb = g >> 3, sl = g & 7;
      const float* up  = U2 + ((bb*16)*8 + sl)*64 + ln;
      const float* spp = S2 + (bb*16)*8 + sl;
      float usum = 0.f, ssum = 0.f;
      #pragma unroll
      for (int t = 0; t < 16; ++t){
        usum += up[t*512];
        ssum += spp[t*8];
      }
      ut[row*72 + ln] = f2b(usum / ssum);
      ht[row*72 + ln] = f2b(slotsC[g*64 + ln]);
    }
    __syncthreads();

    f32x4 axr = {0,0,0,0}, axz = {0,0,0,0}, axn = {0,0,0,0};
    f32x4 ahr = {0,0,0,0}, ahz = {0,0,0,0}, ahn = {0,0,0,0};
    #pragma unroll
    for (int ks = 0; ks < 2; ++ks){
      s16x8 au = *(const s16x8*)(ut + m16*72 + ks*32 + q*8);
      s16x8 ah = *(const s16x8*)(ht + m16*72 + ks*32 + q*8);
      axr = mfma16(au, *(const s16x8*)(wihb + (      cw)*64 + ks*32 + q*8), axr);
      axz = mfma16(au, *(const s16x8*)(wihb + ( 64 + cw)*64 + ks*32 + q*8), axz);
      axn = mfma16(au, *(const s16x8*)(wihb + (128 + cw)*64 + ks*32 + q*8), axn);
      ahr = mfma16(ah, *(const s16x8*)(whhb + (      cw)*64 + ks*32 + q*8), ahr);
      ahz = mfma16(ah, *(const s16x8*)(whhb + ( 64 + cw)*64 + ks*32 + q*8), ahz);
      ahn = mfma16(ah, *(const s16x8*)(whhb + (128 + cw)*64 + ks*32 + q*8), ahn);
    }
    const float bxr = bih[cw], bxz = bih[64+cw], bxn = bih[128+cw];
    const float bhr = bhh[cw], bhz = bhh[64+cw], bhn = bhh[128+cw];
    float sp[4];
    #pragma unroll
    for (int rr = 0; rr < 4; ++rr){
      float xr = axr[rr] + bxr, xz = axz[rr] + bxz, xnv = axn[rr] + bxn;
      float hr = ahr[rr] + bhr, hz = ahz[rr] + bhz, hn = ahn[rr] + bhn;
      float rg = 1.f / (1.f + expf(-(xr + hr)));
      float zg = 1.f / (1.f + expf(-(xz + hz)));
      float ng = tanhf(xnv + rg*hn);
      float hv = b2f(ht[(q*4 + rr)*72 + cw]);
      sp[rr] = (1.f - zg)*ng + zg*hv;
    }

    float s1[4], s2[4];
    #pragma unroll
    for (int rr = 0; rr < 4; ++rr){
      s1[rr] = rsum16(sp[rr]);
      s2[rr] = rsum16(sp[rr]*sp[rr]);
    }
    if (m16 == 0){
      #pragma unroll
      for (int rr = 0; rr < 4; ++rr){ redS[q*4+rr][w] = s1[rr]; redQ[q*4+rr][w] = s2[rr]; }
    }
    __syncthreads();
    float sl_[4];
    {
      const float gm = gmlp[cw], bm = bmlp[cw];
      #pragma unroll
      for (int rr = 0; rr < 4; ++rr){
        f32x4 aS = *(const f32x4*)redS[q*4+rr];
        f32x4 aQ = *(const f32x4*)redQ[q*4+rr];
        float tS = aS[0]+aS[1]+aS[2]+aS[3];
        float tQ = aQ[0]+aQ[1]+aQ[2]+aQ[3];
        float mean = tS*(1.f/64.f);
        float var  = tQ*(1.f/64.f) - mean*mean;
        float rs = rsqrtf(var + 1e-5f);
        sl_[rr] = (sp[rr] - mean)*rs*gm + bm;
        st[(q*4+rr)*72 + cw] = f2b(sl_[rr]);
      }
    }
    __syncthreads();

    #pragma unroll
    for (int t2 = 0; t2 < 2; ++t2){
      int nt = w*2 + t2;
      int col = nt*16 + m16;
      f32x4 acc = {0,0,0,0};
      #pragma unroll
      for (int ks = 0; ks < 2; ++ks){
        s16x8 a = *(const s16x8*)(st + m16*72 + ks*32 + q*8);
        acc = mfma16(a, *(const s16x8*)(w1b + col*64 + ks*32 + q*8), acc);
      }
      float bb = b1p[col];
      #pragma unroll
      for (int rr = 0; rr < 4; ++rr)
        hid[(q*4+rr)*136 + col] = f2b(fmaxf(acc[rr] + bb, 0.f));
    }
    __syncthreads();

    {
      f32x4 acc = {0,0,0,0};
      #pragma unroll
      for (int ks = 0; ks < 4; ++ks){
        s16x8 a = *(const s16x8*)(hid + m16*136 + ks*32 + q*8);
        acc = mfma16(a, *(const s16x8*)(w2b + cw*128 + ks*32 + q*8), acc);
      }
      float bb = b2p[cw];
      #pragma unroll
      for (int rr = 0; rr < 4; ++rr){
        int row = r0 + q*4 + rr;
        outp[row*64 + cw] = sl_[rr] + acc[rr] + bb;
      }
    }
  }
}

// ---------------------------------------------------------------------------
extern "C" void kernel_launch(void* const* d_in, const int* in_sizes, int n_in,
                              void* d_out, int out_size, void* d_ws, size_t ws_size,
                              hipStream_t stream)
{
  const float* x    = (const float*)d_in[0];
  const float* noise= (const float*)d_in[1];
  const float* Wq   = (const float*)d_in[2];
  const float* Wk   = (const float*)d_in[3];
  const float* Wv   = (const float*)d_in[4];
  const float* ling = (const float*)d_in[5];
  const float* linb = (const float*)d_in[6];
  const float* gsl  = (const float*)d_in[7];
  const float* bsl  = (const float*)d_in[8];
  const float* gmlp = (const float*)d_in[9];
  const float* bmlp = (const float*)d_in[10];
  const float* wih  = (const float*)d_in[11];
  const float* whh  = (const float*)d_in[12];
  const float* bih  = (const float*)d_in[13];
  const float* bhh  = (const float*)d_in[14];
  const float* w1   = (const float*)d_in[15];
  const float* b1p  = (const float*)d_in[16];
  const float* w2   = (const float*)d_in[17];
  const float* b2p  = (const float*)d_in[18];
  const float* mu   = (const float*)d_in[19];
  const float* lsg  = (const float*)d_in[20];

  char* ws = (char*)d_ws;
  unsigned short* kg   = (unsigned short*)(ws);              // 16 MiB
  unsigned short* vt   = (unsigned short*)(ws + 16777216);   // 16 MiB
  char* base = ws + 33554432;
  unsigned short* qws  = (unsigned short*)(base);            // 64 KiB
  float* slotsA        = (float*)(base + 65536);
  float* slotsB        = (float*)(base + 131072);
  float* slotsC        = (float*)(base + 196608);
  float* U0            = (float*)(base + 262144);            // 1 MiB each
  float* U1            = (float*)(base + 1310720);
  float* U2            = (float*)(base + 2359296);
  float* S0            = (float*)(base + 3407872);           // 16 KiB each
  float* S1            = (float*)(base + 3424256);
  float* S2            = (float*)(base + 3440640);
  unsigned short* wkb  = (unsigned short*)(base + 3457024);  // 16 KiB
  unsigned short* wvb  = (unsigned short*)(base + 3473408);  // 16 KiB
  unsigned short* wall = (unsigned short*)(base + 3489792);  // 88 KiB
  unsigned int* bar    = (unsigned int*)(base + 3579904);    // barrier state
  float* outp          = (float*)d_out;

  hipLaunchKernelGGL(k_wpack, dim3(60), dim3(256), 0, stream,
                     Wk, Wv, wih, whh, w1, w2, Wq, wkb, wvb, wall, bar);
  hipLaunchKernelGGL(k_lnkv5, dim3(1040), dim3(256), 0, stream,
                     x, wkb, wvb, ling, linb, kg, vt,
                     noise, mu, lsg, gsl, bsl, Wq, slotsA, qws);
  hipLaunchKernelGGL(k_iter, dim3(512), dim3(256), 0, stream,
                     kg, vt, qws, wall, bih, bhh, b1p, b2p,
                     gmlp, bmlp, gsl, bsl,
                     U0, U1, U2, S0, S1, S2,
                     slotsA, slotsB, slotsC, outp, bar);
  (void)in_sizes; (void)n_in; (void)out_size; (void)ws_size;
}

// Round 10
// 233.704 us; speedup vs baseline: 2.0770x; 2.0770x over previous
//
#include <hip/hip_runtime.h>

typedef __attribute__((ext_vector_type(8))) short s16x8;
typedef __attribute__((ext_vector_type(4))) float f32x4;

#define DEV static __device__ __forceinline__

DEV float b2f(unsigned short u){
  unsigned int i = ((unsigned int)u) << 16;
  float f; __builtin_memcpy(&f, &i, 4); return f;
}
DEV unsigned short f2b(float f){
  unsigned int i; __builtin_memcpy(&i, &f, 4);
  i = i + 0x7fffu + ((i >> 16) & 1u);
  return (unsigned short)(i >> 16);
}
DEV f32x4 mfma16(s16x8 a, s16x8 b, f32x4 c){
  return __builtin_amdgcn_mfma_f32_16x16x32_bf16(a, b, c, 0, 0, 0);
}
// load 8 consecutive f32 (32B-aligned) -> bf16 A/B fragment
DEV s16x8 ld8f(const float* p){
  const float4* q4 = (const float4*)p;
  float4 a = q4[0], b = q4[1];
  s16x8 r;
  r[0]=(short)f2b(a.x); r[1]=(short)f2b(a.y); r[2]=(short)f2b(a.z); r[3]=(short)f2b(a.w);
  r[4]=(short)f2b(b.x); r[5]=(short)f2b(b.y); r[6]=(short)f2b(b.z); r[7]=(short)f2b(b.w);
  return r;
}

// DPP-based 16-lane all-reduce sum
template<int C> DEV float dpp_addstep(float x){
  int y = __builtin_amdgcn_update_dpp(0, __builtin_bit_cast(int, x), C, 0xF, 0xF, true);
  return x + __builtin_bit_cast(float, y);
}
DEV float rsum16(float v){
  v = dpp_addstep<0xB1>(v);   // quad_perm xor1
  v = dpp_addstep<0x4E>(v);   // quad_perm xor2
  v = dpp_addstep<0x141>(v);  // row_half_mirror
  v = dpp_addstep<0x140>(v);  // row_mirror
  return v;
}

// ---------------------------------------------------------------------------
// K1 (round-14): LN(x) -> k (plain [b][n][h] bf16), v^T ([b][h][n] bf16),
// with Wk/Wv converted f32->bf16 INLINE (k_wpack dispatch eliminated: its
// ~3us + ~5us launch boundary were pure critical-path serial time).
// INVARIANT: each wave covers TWO adjacent 16-col vt tiles (64B/row from one
// wave back-to-back) -- this is what lets L2 merge the sub-line stores
// (verified: FETCH 33MB / WRITE 33MB, 41.7us).
// Tail blocks: slot-init + pack wall (GRU/MLP/Wq weights bf16; consumed only
// by attn launches >= 1, far after this kernel retires).
// wall layout (elements): wih@0 whh@12288 w1@24576 w2@32768 wq@40960.
// ---------------------------------------------------------------------------
__global__ __launch_bounds__(256, 4) void k_lnkv6(
    const float* __restrict__ x,
    const float* __restrict__ Wk,
    const float* __restrict__ Wv,
    const float* __restrict__ lg,
    const float* __restrict__ lb,
    unsigned short* __restrict__ kg,
    unsigned short* __restrict__ vt,
    // tail-block args
    const float* __restrict__ noise,
    const float* __restrict__ mu,
    const float* __restrict__ lsg,
    const float* __restrict__ gsl,
    const float* __restrict__ bsl,
    const float* __restrict__ Wq,
    const float* __restrict__ wih, const float* __restrict__ whh,
    const float* __restrict__ w1, const float* __restrict__ w2,
    float* __restrict__ slots,
    unsigned short* __restrict__ qws,
    unsigned short* __restrict__ wall)
{
  __shared__ __align__(16) unsigned int xs[128 * 68];
  const int tid = threadIdx.x;
  const int w = tid >> 6, ln = tid & 63;
  const int m16 = ln & 15, q = ln >> 4;

  if (blockIdx.x >= 1024){
    // ------------- tail: slot-init + wall weight pack (16 blocks) ---------
    unsigned short* st = (unsigned short*)xs;
    float (*redS)[4] = (float(*)[4])((char*)xs + 2304);
    float (*redQ)[4] = (float(*)[4])((char*)xs + 2560);
    const int bi = blockIdx.x - 1024;
    const int r0 = bi * 16;
    const int cw = w*16 + m16;

    // wall pack: 45056 elems, 4096 threads x 4 elems x 3 iters
    {
      const int t2 = bi*256 + tid;
      #pragma unroll
      for (int i = 0; i < 3; ++i){
        int off = t2*4 + i*16384;
        if (off < 45056){
          const float* src;
          if      (off < 12288) src = wih + off;
          else if (off < 24576) src = whh + off - 12288;
          else if (off < 32768) src = w1  + off - 24576;
          else if (off < 40960) src = w2  + off - 32768;
          else                  src = Wq  + off - 40960;
          float4 v = *(const float4*)src;
          ushort4 o;
          o.x = f2b(v.x); o.y = f2b(v.y); o.z = f2b(v.z); o.w = f2b(v.w);
          *(ushort4*)(wall + off) = o;
        }
      }
    }

    float sl[4], s1[4], s2[4];
    #pragma unroll
    for (int rr = 0; rr < 4; ++rr){
      int row = r0 + q*4 + rr;
      int k = row & 7;
      float v = mu[k*64 + cw] + (log1pf(expf(lsg[k*64 + cw])) + 1e-5f) * noise[row*64 + cw];
      sl[rr] = v;
      slots[row*64 + cw] = v;
      s1[rr] = rsum16(v);
      s2[rr] = rsum16(v*v);
    }
    if (m16 == 0){
      #pragma unroll
      for (int rr = 0; rr < 4; ++rr){ redS[q*4+rr][w] = s1[rr]; redQ[q*4+rr][w] = s2[rr]; }
    }
    __syncthreads();
    {
      const float gs = gsl[cw], bs = bsl[cw];
      #pragma unroll
      for (int rr = 0; rr < 4; ++rr){
        f32x4 aS = *(const f32x4*)redS[q*4+rr];
        f32x4 aQ = *(const f32x4*)redQ[q*4+rr];
        float tS = aS[0]+aS[1]+aS[2]+aS[3];
        float tQ = aQ[0]+aQ[1]+aQ[2]+aQ[3];
        float mean = tS*(1.f/64.f);
        float var  = tQ*(1.f/64.f) - mean*mean;
        float rs = rsqrtf(var + 1e-5f);
        float sq = (sl[rr] - mean)*rs*gs + bs;
        st[(q*4+rr)*72 + cw] = f2b(sq);
      }
    }
    __syncthreads();
    {
      f32x4 acc = {0,0,0,0};
      #pragma unroll
      for (int ks = 0; ks < 2; ++ks){
        s16x8 a = *(const s16x8*)(st + m16*72 + ks*32 + q*8);
        acc = mfma16(a, ld8f(Wq + cw*64 + ks*32 + q*8), acc);
      }
      #pragma unroll
      for (int rr = 0; rr < 4; ++rr){
        int row = r0 + q*4 + rr;
        int bb_ = row >> 3, kk = row & 7;
        qws[(bb_*16 + kk)*64 + cw] = f2b(acc[rr] * 0.125f);
      }
      int b0 = bi * 2;
      ((unsigned int*)(qws + (b0*16 + 8)*64))[tid] = 0u;
      ((unsigned int*)(qws + ((b0+1)*16 + 8)*64))[tid] = 0u;
    }
    return;
  }

  // ---------------- LN + KV path (1024 blocks, 128 rows each) -------------
  const int b = blockIdx.x >> 5;
  const int nbase = (blockIdx.x & 31) << 7;
  const long rowg0 = (long)b * 4096 + nbase;

  {
    const int c = m16;
    const float4 gA = *(const float4*)(lg + c*4);
    const float4 gB = *(const float4*)(lg + 64 + c*4);
    const float4 bA = *(const float4*)(lb + c*4);
    const float4 bB = *(const float4*)(lb + 64 + c*4);
    const float* base = x + (rowg0 + w*32 + q)*128;

    float4 va[2], vb[2];
    va[0] = *(const float4*)(base + c*4);
    vb[0] = *(const float4*)(base + 64 + c*4);
    #pragma unroll
    for (int p = 0; p < 8; ++p){
      const int cur = p & 1, nxt = cur ^ 1;
      if (p < 7){
        va[nxt] = *(const float4*)(base + (p+1)*512 + c*4);
        vb[nxt] = *(const float4*)(base + (p+1)*512 + 64 + c*4);
      }
      float4 u = va[cur], t = vb[cur];
      float s1 = (u.x + u.y) + (u.z + u.w) + (t.x + t.y) + (t.z + t.w);
      float s2 = (u.x*u.x + u.y*u.y) + (u.z*u.z + u.w*u.w)
               + (t.x*t.x + t.y*t.y) + (t.z*t.z + t.w*t.w);
      s1 = rsum16(s1);
      s2 = rsum16(s2);
      float mean = s1 * (1.f/128.f);
      float var  = s2 * (1.f/128.f) - mean*mean;
      float rs = rsqrtf(var + 1e-5f);
      float y0 = (u.x - mean)*rs*gA.x + bA.x;
      float y1 = (u.y - mean)*rs*gA.y + bA.y;
      float y2 = (u.z - mean)*rs*gA.z + bA.z;
      float y3 = (u.w - mean)*rs*gA.w + bA.w;
      float y4 = (t.x - mean)*rs*gB.x + bB.x;
      float y5 = (t.y - mean)*rs*gB.y + bB.y;
      float y6 = (t.z - mean)*rs*gB.z + bB.z;
      float y7 = (t.w - mean)*rs*gB.w + bB.w;
      uint2 pkA, pkB;
      pkA.x = (unsigned int)f2b(y0) | ((unsigned int)f2b(y1) << 16);
      pkA.y = (unsigned int)f2b(y2) | ((unsigned int)f2b(y3) << 16);
      pkB.x = (unsigned int)f2b(y4) | ((unsigned int)f2b(y5) << 16);
      pkB.y = (unsigned int)f2b(y6) | ((unsigned int)f2b(y7) << 16);
      const int r = w*32 + p*4 + q;
      *(uint2*)&xs[r*68 + c*2] = pkA;
      *(uint2*)&xs[r*68 + 32 + c*2] = pkB;
    }
  }

  // B-fragments: inline f32->bf16 conversion (replaces the pre-packed load)
  s16x8 bw[4][4];
  #pragma unroll
  for (int t = 0; t < 4; ++t)
    #pragma unroll
    for (int kb = 0; kb < 4; ++kb)
      bw[kb][t] = ld8f(Wk + (t*16 + m16)*128 + kb*32 + q*8);

  __syncthreads();

  const f32x4 zf = {0.f, 0.f, 0.f, 0.f};

  #pragma unroll
  for (int mi = 0; mi < 2; ++mi){
    int n0 = (w*2 + mi) * 16;
    f32x4 acc[4];
    #pragma unroll
    for (int t = 0; t < 4; ++t) acc[t] = zf;
    #pragma unroll
    for (int kb = 0; kb < 4; ++kb){
      s16x8 af = *(const s16x8*)((const unsigned short*)(xs + (n0 + m16)*68) + kb*32 + q*8);
      #pragma unroll
      for (int t = 0; t < 4; ++t)
        acc[t] = mfma16(af, bw[kb][t], acc[t]);
    }
    #pragma unroll
    for (int t = 0; t < 4; ++t){
      int h = t*16 + m16;
      #pragma unroll
      for (int rr = 0; rr < 4; ++rr){
        long n = rowg0 + n0 + q*4 + rr;
        kg[n*64 + h] = f2b(acc[t][rr]);
      }
    }
  }

  #pragma unroll
  for (int t = 0; t < 4; ++t)
    #pragma unroll
    for (int kb = 0; kb < 4; ++kb)
      bw[kb][t] = ld8f(Wv + (t*16 + m16)*128 + kb*32 + q*8);

  #pragma unroll
  for (int mi = 0; mi < 2; ++mi){
    int n0 = (w*2 + mi) * 16;
    f32x4 acc[4];
    #pragma unroll
    for (int t = 0; t < 4; ++t) acc[t] = zf;
    #pragma unroll
    for (int kb = 0; kb < 4; ++kb){
      s16x8 af = *(const s16x8*)((const unsigned short*)(xs + (n0 + m16)*68) + kb*32 + q*8);
      #pragma unroll
      for (int t = 0; t < 4; ++t)
        acc[t] = mfma16(af, bw[kb][t], acc[t]);
    }
    #pragma unroll
    for (int t = 0; t < 4; ++t){
      int h = t*16 + m16;
      unsigned int p0 = (unsigned int)f2b(acc[t][0]) | ((unsigned int)f2b(acc[t][1]) << 16);
      unsigned int p1 = (unsigned int)f2b(acc[t][2]) | ((unsigned int)f2b(acc[t][3]) << 16);
      uint2 pv; pv.x = p0; pv.y = p1;
      long off = ((long)b*64 + h)*4096 + nbase + n0 + q*4;
      *(uint2*)(vt + off) = pv;
    }
  }
}

// ---------------------------------------------------------------------------
// K3: [GRU prologue (it>0, sums 16 U/S tile-partials)] + attention.
// BYTE-IDENTICAL to the verified round-7 k_attn3 (201.9us, absmax 0.0390625).
// ---------------------------------------------------------------------------
__global__ __launch_bounds__(256) void k_attn3(
    const unsigned short* __restrict__ kg,
    const unsigned short* __restrict__ vt,
    const unsigned short* __restrict__ qws,   // it==0 only
    const unsigned short* __restrict__ wall,  // packed [wih|whh|w1|w2|wq] bf16
    const float* __restrict__ bih, const float* __restrict__ bhh,
    const float* __restrict__ b1p, const float* __restrict__ b2p,
    const float* __restrict__ gmlp, const float* __restrict__ bmlp,
    const float* __restrict__ gsl, const float* __restrict__ bsl,
    const float* __restrict__ Up_in, const float* __restrict__ Sp_in,
    float* __restrict__ Up_out, float* __restrict__ Sp_out,
    const float* __restrict__ slin, float* __restrict__ slout,
    int it)
{
  __shared__ float sc[256*17];
  __shared__ unsigned short aT[16*264];
  __shared__ unsigned short ut[16*72], ht[16*72], st[16*72], hid[16*136];
  __shared__ unsigned short qloc[16*72];
  __shared__ __align__(16) float redS[16][4];
  __shared__ __align__(16) float redQ[16][4];
  __shared__ __align__(16) float redS2[16][4];
  __shared__ __align__(16) float redQ2[16][4];

  const int tid = threadIdx.x;
  const int w = tid >> 6, ln = tid & 63;
  const int m16 = ln & 15, q = ln >> 4;
  const int b = blockIdx.x >> 4;
  const int tile = blockIdx.x & 15;
  const int nbase = tile << 8;

  // ---- prefetch attention operands (independent of prologue) ----
  s16x8 afp[4];
  #pragma unroll
  for (int mi = 0; mi < 4; ++mi){
    int n0 = (w*4 + mi)*16;
    afp[mi] = *(const s16x8*)(kg + ((long)b*4096 + nbase + n0 + m16)*64 + q*8);
  }
  s16x8 afp2[4];
  #pragma unroll
  for (int mi = 0; mi < 4; ++mi){
    int n0 = (w*4 + mi)*16;
    afp2[mi] = *(const s16x8*)(kg + ((long)b*4096 + nbase + n0 + m16)*64 + 32 + q*8);
  }
  s16x8 vtp[8];
  #pragma unroll
  for (int ks = 0; ks < 8; ++ks)
    vtp[ks] = *(const s16x8*)(vt + ((long)b*64 + w*16 + m16)*4096 + nbase + ks*32 + q*8);

  for (int i = tid; i < 8*264; i += 256) aT[8*264 + i] = 0;  // aT slot-pad rows
  if (tid < 128){                                            // qloc pad rows 8..15
    int row = 8 + (tid >> 4), c = (tid & 15)*4;
    ushort4 z4 = {0,0,0,0};
    *(ushort4*)&qloc[row*72 + c] = z4;
  }

  if (it == 0){
    if (tid < 128){
      int row = tid >> 4, c = (tid & 15)*4;
      *(ushort4*)&qloc[row*72 + c] = *(const ushort4*)(qws + (b*16 + row)*64 + c);
    }
  } else {
    // ---- redundant GRU+LN+MLP+LN_sl+q for batch pair (b&~1, b|1) ----
    const int r0 = (b >> 1) * 16;
    const int cw = w*16 + m16;
    const unsigned short* wihb = wall;
    const unsigned short* whhb = wall + 12288;
    const unsigned short* w1b  = wall + 24576;
    const unsigned short* w2b  = wall + 32768;
    const unsigned short* wqb  = wall + 40960;

    #pragma unroll
    for (int p = 0; p < 4; ++p){
      int row = p*4 + w;
      int g = r0 + row;
      int bb = g >> 3, sl = g & 7;
      const float* up  = Up_in + ((bb*16)*8 + sl)*64 + ln;
      const float* spp = Sp_in + (bb*16)*8 + sl;
      float usum = 0.f, ssum = 0.f;
      #pragma unroll
      for (int t = 0; t < 16; ++t){
        usum += up[t*512];
        ssum += spp[t*8];
      }
      ut[row*72 + ln] = f2b(usum / ssum);
      ht[row*72 + ln] = f2b(slin[g*64 + ln]);
    }
    __syncthreads();

    f32x4 axr = {0,0,0,0}, axz = {0,0,0,0}, axn = {0,0,0,0};
    f32x4 ahr = {0,0,0,0}, ahz = {0,0,0,0}, ahn = {0,0,0,0};
    #pragma unroll
    for (int ks = 0; ks < 2; ++ks){
      s16x8 au = *(const s16x8*)(ut + m16*72 + ks*32 + q*8);
      s16x8 ah = *(const s16x8*)(ht + m16*72 + ks*32 + q*8);
      axr = mfma16(au, *(const s16x8*)(wihb + (      cw)*64 + ks*32 + q*8), axr);
      axz = mfma16(au, *(const s16x8*)(wihb + ( 64 + cw)*64 + ks*32 + q*8), axz);
      axn = mfma16(au, *(const s16x8*)(wihb + (128 + cw)*64 + ks*32 + q*8), axn);
      ahr = mfma16(ah, *(const s16x8*)(whhb + (      cw)*64 + ks*32 + q*8), ahr);
      ahz = mfma16(ah, *(const s16x8*)(whhb + ( 64 + cw)*64 + ks*32 + q*8), ahz);
      ahn = mfma16(ah, *(const s16x8*)(whhb + (128 + cw)*64 + ks*32 + q*8), ahn);
    }
    const float bxr = bih[cw], bxz = bih[64+cw], bxn = bih[128+cw];
    const float bhr = bhh[cw], bhz = bhh[64+cw], bhn = bhh[128+cw];
    float sp[4];
    #pragma unroll
    for (int rr = 0; rr < 4; ++rr){
      float xr = axr[rr] + bxr, xz = axz[rr] + bxz, xnv = axn[rr] + bxn;
      float hr = ahr[rr] + bhr, hz = ahz[rr] + bhz, hn = ahn[rr] + bhn;
      float rg = 1.f / (1.f + expf(-(xr + hr)));
      float zg = 1.f / (1.f + expf(-(xz + hz)));
      float ng = tanhf(xnv + rg*hn);
      float hv = b2f(ht[(q*4 + rr)*72 + cw]);
      sp[rr] = (1.f - zg)*ng + zg*hv;
    }

    float s1[4], s2[4];
    #pragma unroll
    for (int rr = 0; rr < 4; ++rr){
      s1[rr] = rsum16(sp[rr]);
      s2[rr] = rsum16(sp[rr]*sp[rr]);
    }
    if (m16 == 0){
      #pragma unroll
      for (int rr = 0; rr < 4; ++rr){ redS[q*4+rr][w] = s1[rr]; redQ[q*4+rr][w] = s2[rr]; }
    }
    __syncthreads();
    float sl_[4];
    {
      const float gm = gmlp[cw], bm = bmlp[cw];
      #pragma unroll
      for (int rr = 0; rr < 4; ++rr){
        f32x4 aS = *(const f32x4*)redS[q*4+rr];
        f32x4 aQ = *(const f32x4*)redQ[q*4+rr];
        float tS = aS[0]+aS[1]+aS[2]+aS[3];
        float tQ = aQ[0]+aQ[1]+aQ[2]+aQ[3];
        float mean = tS*(1.f/64.f);
        float var  = tQ*(1.f/64.f) - mean*mean;
        float rs = rsqrtf(var + 1e-5f);
        sl_[rr] = (sp[rr] - mean)*rs*gm + bm;
        st[(q*4+rr)*72 + cw] = f2b(sl_[rr]);
      }
    }
    __syncthreads();

    // mlp1 (64->128) + relu
    #pragma unroll
    for (int t2 = 0; t2 < 2; ++t2){
      int nt = w*2 + t2;
      int col = nt*16 + m16;
      f32x4 acc = {0,0,0,0};
      #pragma unroll
      for (int ks = 0; ks < 2; ++ks){
        s16x8 a = *(const s16x8*)(st + m16*72 + ks*32 + q*8);
        acc = mfma16(a, *(const s16x8*)(w1b + col*64 + ks*32 + q*8), acc);
      }
      float bb = b1p[col];
      #pragma unroll
      for (int rr = 0; rr < 4; ++rr)
        hid[(q*4+rr)*136 + col] = f2b(fmaxf(acc[rr] + bb, 0.f));
    }
    __syncthreads();

    // mlp2 (128->64) + residual
    float snew[4];
    {
      f32x4 acc = {0,0,0,0};
      #pragma unroll
      for (int ks = 0; ks < 4; ++ks){
        s16x8 a = *(const s16x8*)(hid + m16*136 + ks*32 + q*8);
        acc = mfma16(a, *(const s16x8*)(w2b + cw*128 + ks*32 + q*8), acc);
      }
      float bb = b2p[cw];
      #pragma unroll
      for (int rr = 0; rr < 4; ++rr){
        snew[rr] = sl_[rr] + acc[rr] + bb;
        if ((blockIdx.x & 31) == 0)
          slout[(r0 + q*4 + rr)*64 + cw] = snew[rr];   // one gate block per pair
      }
    }

    // LN_sl(snew) -> q into qloc (own redS2/redQ2: no pre-write barrier)
    #pragma unroll
    for (int rr = 0; rr < 4; ++rr){
      s1[rr] = rsum16(snew[rr]);
      s2[rr] = rsum16(snew[rr]*snew[rr]);
    }
    if (m16 == 0){
      #pragma unroll
      for (int rr = 0; rr < 4; ++rr){ redS2[q*4+rr][w] = s1[rr]; redQ2[q*4+rr][w] = s2[rr]; }
    }
    __syncthreads();
    {
      const float gs = gsl[cw], bs = bsl[cw];
      #pragma unroll
      for (int rr = 0; rr < 4; ++rr){
        f32x4 aS = *(const f32x4*)redS2[q*4+rr];
        f32x4 aQ = *(const f32x4*)redQ2[q*4+rr];
        float tS = aS[0]+aS[1]+aS[2]+aS[3];
        float tQ = aQ[0]+aQ[1]+aQ[2]+aQ[3];
        float mean = tS*(1.f/64.f);
        float var  = tQ*(1.f/64.f) - mean*mean;
        float rs = rsqrtf(var + 1e-5f);
        float sq = (snew[rr] - mean)*rs*gs + bs;
        st[(q*4+rr)*72 + cw] = f2b(sq);
      }
    }
    __syncthreads();
    {
      f32x4 acc = {0,0,0,0};
      #pragma unroll
      for (int ks = 0; ks < 2; ++ks){
        s16x8 a = *(const s16x8*)(st + m16*72 + ks*32 + q*8);
        acc = mfma16(a, *(const s16x8*)(wqb + cw*64 + ks*32 + q*8), acc);
      }
      #pragma unroll
      for (int rr = 0; rr < 4; ++rr){
        int rloc = q*4 + rr;
        if ((rloc >> 3) == (b & 1))
          qloc[(rloc & 7)*72 + cw] = f2b(acc[rr] * 0.125f);
      }
    }
  }
  __syncthreads();

  // ---- attention (kg already in afp/afp2 registers) ----
  s16x8 bq[2];
  #pragma unroll
  for (int ks = 0; ks < 2; ++ks)
    bq[ks] = *(const s16x8*)(qloc + m16*72 + ks*32 + q*8);

  #pragma unroll
  for (int mi = 0; mi < 4; ++mi){
    int n0 = (w*4 + mi)*16;
    f32x4 acc = {0.f, 0.f, 0.f, 0.f};
    acc = mfma16(afp[mi],  bq[0], acc);
    acc = mfma16(afp2[mi], bq[1], acc);
    #pragma unroll
    for (int rr = 0; rr < 4; ++rr)
      sc[(n0 + q*4 + rr)*17 + m16] = acc[rr];
  }
  __syncthreads();

  {
    int r = tid;
    float a8[8];
    float mx = -1e30f;
    #pragma unroll
    for (int j = 0; j < 8; ++j){ a8[j] = sc[r*17 + j]; mx = fmaxf(mx, a8[j]); }
    float ssum = 0.f;
    #pragma unroll
    for (int j = 0; j < 8; ++j){ a8[j] = expf(a8[j] - mx); ssum += a8[j]; }
    float inv = 1.f/ssum;
    #pragma unroll
    for (int j = 0; j < 8; ++j)
      aT[j*264 + r] = f2b(a8[j]*inv + 1e-8f);
  }
  __syncthreads();

  {  // S tile-partials: rsum16 + one xor16 (reduce over 32 lanes)
    int j = tid >> 5, c = tid & 31;
    float p = 0.f;
    #pragma unroll
    for (int i = 0; i < 8; ++i) p += b2f(aT[j*264 + c + 32*i]);
    p = rsum16(p);
    p += __shfl_xor(p, 16);
    if ((tid & 31) == 0) Sp_out[(b*16 + tile)*8 + j] = p;
  }

  {  // U tile-partials: wave w handles h-tile nt = w; vt already in vtp regs
    f32x4 acc = {0.f, 0.f, 0.f, 0.f};
    #pragma unroll
    for (int ks = 0; ks < 8; ++ks){
      s16x8 af = *(const s16x8*)(aT + m16*264 + ks*32 + q*8);
      acc = mfma16(af, vtp[ks], acc);
    }
    float* ub = Up_out + ((b*16 + tile)*8)*64 + w*16 + m16;
    #pragma unroll
    for (int rr = 0; rr < 4; ++rr){
      int slot = q*4 + rr;
      if (slot < 8)
        ub[slot*64] = acc[rr];
    }
  }
}

// ---------------------------------------------------------------------------
// K4: final GRU + LN_mlp + MLP(+residual) -> outp; sums the 16 tile-partials.
// UNCHANGED from round 7.
// ---------------------------------------------------------------------------
__global__ __launch_bounds__(256) void k_gru2(
    const float* __restrict__ Up, const float* __restrict__ Sp,
    const float* __restrict__ slots,
    const float* __restrict__ wih, const float* __restrict__ whh,
    const float* __restrict__ bih, const float* __restrict__ bhh,
    const float* __restrict__ w1, const float* __restrict__ b1p,
    const float* __restrict__ w2, const float* __restrict__ b2p,
    const float* __restrict__ gmlp, const float* __restrict__ bmlp,
    float* __restrict__ outp)
{
  __shared__ unsigned short ut[16*72], ht[16*72], st[16*72], hid[16*136];
  __shared__ __align__(16) float redS[16][4];
  __shared__ __align__(16) float redQ[16][4];
  const int tid = threadIdx.x;
  const int w = tid >> 6, ln = tid & 63;
  const int m16 = ln & 15, q = ln >> 4;
  const int r0 = blockIdx.x * 16;
  const int cw = w*16 + m16;

  #pragma unroll
  for (int p = 0; p < 4; ++p){
    int row = p*4 + w;
    int g = r0 + row;
    int bb = g >> 3, sl = g & 7;
    const float* up  = Up + ((bb*16)*8 + sl)*64 + ln;
    const float* spp = Sp + (bb*16)*8 + sl;
    float usum = 0.f, ssum = 0.f;
    #pragma unroll
    for (int t = 0; t < 16; ++t){
      usum += up[t*512];
      ssum += spp[t*8];
    }
    ut[row*72 + ln] = f2b(usum / ssum);
    ht[row*72 + ln] = f2b(slots[g*64 + ln]);
  }
  __syncthreads();

  f32x4 axr = {0,0,0,0}, axz = {0,0,0,0}, axn = {0,0,0,0};
  f32x4 ahr = {0,0,0,0}, ahz = {0,0,0,0}, ahn = {0,0,0,0};
  #pragma unroll
  for (int ks = 0; ks < 2; ++ks){
    s16x8 au = *(const s16x8*)(ut + m16*72 + ks*32 + q*8);
    s16x8 ah = *(const s16x8*)(ht + m16*72 + ks*32 + q*8);
    axr = mfma16(au, ld8f(wih + (      cw)*64 + ks*32 + q*8), axr);
    axz = mfma16(au, ld8f(wih + ( 64 + cw)*64 + ks*32 + q*8), axz);
    axn = mfma16(au, ld8f(wih + (128 + cw)*64 + ks*32 + q*8), axn);
    ahr = mfma16(ah, ld8f(whh + (      cw)*64 + ks*32 + q*8), ahr);
    ahz = mfma16(ah, ld8f(whh + ( 64 + cw)*64 + ks*32 + q*8), ahz);
    ahn = mfma16(ah, ld8f(whh + (128 + cw)*64 + ks*32 + q*8), ahn);
  }
  const float bxr = bih[cw], bxz = bih[64+cw], bxn = bih[128+cw];
  const float bhr = bhh[cw], bhz = bhh[64+cw], bhn = bhh[128+cw];
  float sp[4];
  #pragma unroll
  for (int rr = 0; rr < 4; ++rr){
    float xr = axr[rr] + bxr, xz = axz[rr] + bxz, xnv = axn[rr] + bxn;
    float hr = ahr[rr] + bhr, hz = ahz[rr] + bhz, hn = ahn[rr] + bhn;
    float rg = 1.f / (1.f + expf(-(xr + hr)));
    float zg = 1.f / (1.f + expf(-(xz + hz)));
    float ng = tanhf(xnv + rg*hn);
    float hv = b2f(ht[(q*4 + rr)*72 + cw]);
    sp[rr] = (1.f - zg)*ng + zg*hv;
  }

  float s1[4], s2[4];
  #pragma unroll
  for (int rr = 0; rr < 4; ++rr){
    s1[rr] = rsum16(sp[rr]);
    s2[rr] = rsum16(sp[rr]*sp[rr]);
  }
  if (m16 == 0){
    #pragma unroll
    for (int rr = 0; rr < 4; ++rr){ redS[q*4+rr][w] = s1[rr]; redQ[q*4+rr][w] = s2[rr]; }
  }
  __syncthreads();
  float sl_[4];
  {
    const float gm = gmlp[cw], bm = bmlp[cw];
    #pragma unroll
    for (int rr = 0; rr < 4; ++rr){
      f32x4 aS = *(const f32x4*)redS[q*4+rr];
      f32x4 aQ = *(const f32x4*)redQ[q*4+rr];
      float tS = aS[0]+aS[1]+aS[2]+aS[3];
      float tQ = aQ[0]+aQ[1]+aQ[2]+aQ[3];
      float mean = tS*(1.f/64.f);
      float var  = tQ*(1.f/64.f) - mean*mean;
      float rs = rsqrtf(var + 1e-5f);
      sl_[rr] = (sp[rr] - mean)*rs*gm + bm;
      st[(q*4+rr)*72 + cw] = f2b(sl_[rr]);
    }
  }
  __syncthreads();

  #pragma unroll
  for (int t2 = 0; t2 < 2; ++t2){
    int nt = w*2 + t2;
    int col = nt*16 + m16;
    f32x4 acc = {0,0,0,0};
    #pragma unroll
    for (int ks = 0; ks < 2; ++ks){
      s16x8 a = *(const s16x8*)(st + m16*72 + ks*32 + q*8);
      acc = mfma16(a, ld8f(w1 + col*64 + ks*32 + q*8), acc);
    }
    float bb = b1p[col];
    #pragma unroll
    for (int rr = 0; rr < 4; ++rr)
      hid[(q*4+rr)*136 + col] = f2b(fmaxf(acc[rr] + bb, 0.f));
  }
  __syncthreads();

  {
    f32x4 acc = {0,0,0,0};
    #pragma unroll
    for (int ks = 0; ks < 4; ++ks){
      s16x8 a = *(const s16x8*)(hid + m16*136 + ks*32 + q*8);
      acc = mfma16(a, ld8f(w2 + cw*128 + ks*32 + q*8), acc);
    }
    float bb = b2p[cw];
    #pragma unroll
    for (int rr = 0; rr < 4; ++rr){
      int row = r0 + q*4 + rr;
      outp[row*64 + cw] = sl_[rr] + acc[rr] + bb;
    }
  }
}

// ---------------------------------------------------------------------------
extern "C" void kernel_launch(void* const* d_in, const int* in_sizes, int n_in,
                              void* d_out, int out_size, void* d_ws, size_t ws_size,
                              hipStream_t stream)
{
  const float* x    = (const float*)d_in[0];
  const float* noise= (const float*)d_in[1];
  const float* Wq   = (const float*)d_in[2];
  const float* Wk   = (const float*)d_in[3];
  const float* Wv   = (const float*)d_in[4];
  const float* ling = (const float*)d_in[5];
  const float* linb = (const float*)d_in[6];
  const float* gsl  = (const float*)d_in[7];
  const float* bsl  = (const float*)d_in[8];
  const float* gmlp = (const float*)d_in[9];
  const float* bmlp = (const float*)d_in[10];
  const float* wih  = (const float*)d_in[11];
  const float* whh  = (const float*)d_in[12];
  const float* bih  = (const float*)d_in[13];
  const float* bhh  = (const float*)d_in[14];
  const float* w1   = (const float*)d_in[15];
  const float* b1p  = (const float*)d_in[16];
  const float* w2   = (const float*)d_in[17];
  const float* b2p  = (const float*)d_in[18];
  const float* mu   = (const float*)d_in[19];
  const float* lsg  = (const float*)d_in[20];

  char* ws = (char*)d_ws;
  unsigned short* kg   = (unsigned short*)(ws);              // 16 MiB
  unsigned short* vt   = (unsigned short*)(ws + 16777216);   // 16 MiB
  char* base = ws + 33554432;
  unsigned short* qws  = (unsigned short*)(base);            // 64 KiB
  float* slotsA        = (float*)(base + 65536);             // 64 KiB
  float* slotsB        = (float*)(base + 131072);
  float* slotsC        = (float*)(base + 196608);
  float* UA            = (float*)(base + 262144);            // 1 MiB partials
  float* UB            = (float*)(base + 1310720);           // 1 MiB
  float* SA            = (float*)(base + 2359296);           // 16 KiB
  float* SB            = (float*)(base + 2375680);           // 16 KiB
  unsigned short* wall = (unsigned short*)(base + 2392064);  // 88 KiB packed weights
  float* outp          = (float*)d_out;

  hipLaunchKernelGGL(k_lnkv6, dim3(1040), dim3(256), 0, stream,
                     x, Wk, Wv, ling, linb, kg, vt,
                     noise, mu, lsg, gsl, bsl, Wq, wih, whh, w1, w2,
                     slotsA, qws, wall);
  // it=0: q from qws; write iter-0 partials into UA/SA
  hipLaunchKernelGGL(k_attn3, dim3(512), dim3(256), 0, stream,
                     kg, vt, qws, wall, bih, bhh, b1p, b2p, gmlp, bmlp, gsl, bsl,
                     UA, SA, UA, SA, slotsA, slotsA, 0);
  // it=1: gru(sum UA/SA, slotsA)->slotsB + q; write iter-1 partials into UB/SB
  hipLaunchKernelGGL(k_attn3, dim3(512), dim3(256), 0, stream,
                     kg, vt, qws, wall, bih, bhh, b1p, b2p, gmlp, bmlp, gsl, bsl,
                     UA, SA, UB, SB, slotsA, slotsB, 1);
  // it=2: gru(sum UB/SB, slotsB)->slotsC + q; write iter-2 partials into UA/SA
  hipLaunchKernelGGL(k_attn3, dim3(512), dim3(256), 0, stream,
                     kg, vt, qws, wall, bih, bhh, b1p, b2p, gmlp, bmlp, gsl, bsl,
                     UB, SB, UA, SA, slotsB, slotsC, 2);
  // final gru(sum UA/SA, slotsC) -> outp
  hipLaunchKernelGGL(k_gru2, dim3(16), dim3(256), 0, stream, UA, SA, slotsC,
                     wih, whh, bih, bhh, w1, b1p, w2, b2p, gmlp, bmlp, outp);
  (void)in_sizes; (void)n_in; (void)out_size; (void)ws_size;
}

// Round 11
// 201.399 us; speedup vs baseline: 2.4102x; 1.1604x over previous
//
#include <hip/hip_runtime.h>

typedef __attribute__((ext_vector_type(8))) short s16x8;
typedef __attribute__((ext_vector_type(4))) float f32x4;

#define DEV static __device__ __forceinline__

DEV float b2f(unsigned short u){
  unsigned int i = ((unsigned int)u) << 16;
  float f; __builtin_memcpy(&f, &i, 4); return f;
}
DEV unsigned short f2b(float f){
  unsigned int i; __builtin_memcpy(&i, &f, 4);
  i = i + 0x7fffu + ((i >> 16) & 1u);
  return (unsigned short)(i >> 16);
}
DEV f32x4 mfma16(s16x8 a, s16x8 b, f32x4 c){
  return __builtin_amdgcn_mfma_f32_16x16x32_bf16(a, b, c, 0, 0, 0);
}
// load 8 consecutive f32 (32B-aligned) -> bf16 A/B fragment
DEV s16x8 ld8f(const float* p){
  const float4* q4 = (const float4*)p;
  float4 a = q4[0], b = q4[1];
  s16x8 r;
  r[0]=(short)f2b(a.x); r[1]=(short)f2b(a.y); r[2]=(short)f2b(a.z); r[3]=(short)f2b(a.w);
  r[4]=(short)f2b(b.x); r[5]=(short)f2b(b.y); r[6]=(short)f2b(b.z); r[7]=(short)f2b(b.w);
  return r;
}

// DPP-based 16-lane all-reduce sum
template<int C> DEV float dpp_addstep(float x){
  int y = __builtin_amdgcn_update_dpp(0, __builtin_bit_cast(int, x), C, 0xF, 0xF, true);
  return x + __builtin_bit_cast(float, y);
}
DEV float rsum16(float v){
  v = dpp_addstep<0xB1>(v);   // quad_perm xor1
  v = dpp_addstep<0x4E>(v);   // quad_perm xor2
  v = dpp_addstep<0x141>(v);  // row_half_mirror
  v = dpp_addstep<0x140>(v);  // row_mirror
  return v;
}

// ---------------------------------------------------------------------------
// K0: one-shot pack of ALL weights -> bf16. (Round-9 lesson: do NOT inline
// this into k_lnkv -- conversion code between barrier and stores breaks the
// inter-wave store timing the vt write-merge depends on: 33->93MB writes.)
// wall layout (elements): wih@0 whh@12288 w1@24576 w2@32768 wq@40960.
// ---------------------------------------------------------------------------
__global__ __launch_bounds__(256) void k_wpack(
    const float* __restrict__ Wk, const float* __restrict__ Wv,
    const float* __restrict__ wih, const float* __restrict__ whh,
    const float* __restrict__ w1, const float* __restrict__ w2,
    const float* __restrict__ Wq,
    unsigned short* __restrict__ wkb, unsigned short* __restrict__ wvb,
    unsigned short* __restrict__ wall)
{
  int t = blockIdx.x * 256 + threadIdx.x;
  int off = t * 4;
  const float* src; unsigned short* dst;
  if      (off <  8192){ src = Wk  + off;         dst = wkb  + off; }
  else if (off < 16384){ src = Wv  + off -  8192; dst = wvb  + off - 8192; }
  else if (off < 28672){ src = wih + off - 16384; dst = wall + off - 16384; }
  else if (off < 40960){ src = whh + off - 28672; dst = wall + off - 16384; }
  else if (off < 49152){ src = w1  + off - 40960; dst = wall + off - 16384; }
  else if (off < 57344){ src = w2  + off - 49152; dst = wall + off - 16384; }
  else                 { src = Wq  + off - 57344; dst = wall + off - 16384; }
  float4 v = *(const float4*)src;
  ushort4 o;
  o.x = f2b(v.x); o.y = f2b(v.y); o.z = f2b(v.z); o.w = f2b(v.w);
  *(ushort4*)dst = o;
}

// ---------------------------------------------------------------------------
// K1: LN(x) -> k (plain [b][n][h] bf16), v^T ([b][h][n] bf16).
// INVARIANT (verified rounds 4/7; violated+confirmed rounds 2/3/9): each
// wave covers TWO adjacent 16-col vt tiles AND no extra code between the
// barrier and the stores -- L2 merges the cross-wave 64B half-lines only
// when co-owning waves store within the merge window.
// Round-10 change: phase-1 x-prefetch 2 -> 4 slots (3 passes ahead). Ends
// before the barrier => store timing untouched; raises MLP during LN.
// ---------------------------------------------------------------------------
__global__ __launch_bounds__(256, 4) void k_lnkv7(
    const float* __restrict__ x,
    const unsigned short* __restrict__ wkb,
    const unsigned short* __restrict__ wvb,
    const float* __restrict__ lg,
    const float* __restrict__ lb,
    unsigned short* __restrict__ kg,
    unsigned short* __restrict__ vt,
    // init tail-block args
    const float* __restrict__ noise,
    const float* __restrict__ mu,
    const float* __restrict__ lsg,
    const float* __restrict__ gsl,
    const float* __restrict__ bsl,
    const float* __restrict__ Wq,
    float* __restrict__ slots,
    unsigned short* __restrict__ qws)
{
  __shared__ __align__(16) unsigned int xs[128 * 68];
  const int tid = threadIdx.x;
  const int w = tid >> 6, ln = tid & 63;
  const int m16 = ln & 15, q = ln >> 4;

  if (blockIdx.x >= 1024){
    // ---------------- slot-init path (16 tail blocks) ----------------
    unsigned short* st = (unsigned short*)xs;
    float (*redS)[4] = (float(*)[4])((char*)xs + 2304);
    float (*redQ)[4] = (float(*)[4])((char*)xs + 2560);
    const int bi = blockIdx.x - 1024;
    const int r0 = bi * 16;
    const int cw = w*16 + m16;

    float sl[4], s1[4], s2[4];
    #pragma unroll
    for (int rr = 0; rr < 4; ++rr){
      int row = r0 + q*4 + rr;
      int k = row & 7;
      float v = mu[k*64 + cw] + (log1pf(expf(lsg[k*64 + cw])) + 1e-5f) * noise[row*64 + cw];
      sl[rr] = v;
      slots[row*64 + cw] = v;
      s1[rr] = rsum16(v);
      s2[rr] = rsum16(v*v);
    }
    if (m16 == 0){
      #pragma unroll
      for (int rr = 0; rr < 4; ++rr){ redS[q*4+rr][w] = s1[rr]; redQ[q*4+rr][w] = s2[rr]; }
    }
    __syncthreads();
    {
      const float gs = gsl[cw], bs = bsl[cw];
      #pragma unroll
      for (int rr = 0; rr < 4; ++rr){
        f32x4 aS = *(const f32x4*)redS[q*4+rr];
        f32x4 aQ = *(const f32x4*)redQ[q*4+rr];
        float tS = aS[0]+aS[1]+aS[2]+aS[3];
        float tQ = aQ[0]+aQ[1]+aQ[2]+aQ[3];
        float mean = tS*(1.f/64.f);
        float var  = tQ*(1.f/64.f) - mean*mean;
        float rs = rsqrtf(var + 1e-5f);
        float sq = (sl[rr] - mean)*rs*gs + bs;
        st[(q*4+rr)*72 + cw] = f2b(sq);
      }
    }
    __syncthreads();
    {
      f32x4 acc = {0,0,0,0};
      #pragma unroll
      for (int ks = 0; ks < 2; ++ks){
        s16x8 a = *(const s16x8*)(st + m16*72 + ks*32 + q*8);
        acc = mfma16(a, ld8f(Wq + cw*64 + ks*32 + q*8), acc);
      }
      #pragma unroll
      for (int rr = 0; rr < 4; ++rr){
        int row = r0 + q*4 + rr;
        int bb_ = row >> 3, kk = row & 7;
        qws[(bb_*16 + kk)*64 + cw] = f2b(acc[rr] * 0.125f);
      }
      int b0 = bi * 2;
      ((unsigned int*)(qws + (b0*16 + 8)*64))[tid] = 0u;
      ((unsigned int*)(qws + ((b0+1)*16 + 8)*64))[tid] = 0u;
    }
    return;
  }

  // ---------------- LN + KV path (1024 blocks, 128 rows each) -------------
  const int b = blockIdx.x >> 5;
  const int nbase = (blockIdx.x & 31) << 7;
  const long rowg0 = (long)b * 4096 + nbase;

  {
    const int c = m16;
    const float4 gA = *(const float4*)(lg + c*4);
    const float4 gB = *(const float4*)(lg + 64 + c*4);
    const float4 bA = *(const float4*)(lb + c*4);
    const float4 bB = *(const float4*)(lb + 64 + c*4);
    const float* base = x + (rowg0 + w*32 + q)*128;

    // 4-slot ring, 3 passes prefetched ahead
    float4 va[4], vb[4];
    #pragma unroll
    for (int i = 0; i < 3; ++i){
      va[i] = *(const float4*)(base + i*512 + c*4);
      vb[i] = *(const float4*)(base + i*512 + 64 + c*4);
    }
    #pragma unroll
    for (int p = 0; p < 8; ++p){
      const int cur = p & 3;
      if (p < 5){
        const int nxt = (p+3) & 3;
        va[nxt] = *(const float4*)(base + (p+3)*512 + c*4);
        vb[nxt] = *(const float4*)(base + (p+3)*512 + 64 + c*4);
      }
      float4 u = va[cur], t = vb[cur];
      float s1 = (u.x + u.y) + (u.z + u.w) + (t.x + t.y) + (t.z + t.w);
      float s2 = (u.x*u.x + u.y*u.y) + (u.z*u.z + u.w*u.w)
               + (t.x*t.x + t.y*t.y) + (t.z*t.z + t.w*t.w);
      s1 = rsum16(s1);
      s2 = rsum16(s2);
      float mean = s1 * (1.f/128.f);
      float var  = s2 * (1.f/128.f) - mean*mean;
      float rs = rsqrtf(var + 1e-5f);
      float y0 = (u.x - mean)*rs*gA.x + bA.x;
      float y1 = (u.y - mean)*rs*gA.y + bA.y;
      float y2 = (u.z - mean)*rs*gA.z + bA.z;
      float y3 = (u.w - mean)*rs*gA.w + bA.w;
      float y4 = (t.x - mean)*rs*gB.x + bB.x;
      float y5 = (t.y - mean)*rs*gB.y + bB.y;
      float y6 = (t.z - mean)*rs*gB.z + bB.z;
      float y7 = (t.w - mean)*rs*gB.w + bB.w;
      uint2 pkA, pkB;
      pkA.x = (unsigned int)f2b(y0) | ((unsigned int)f2b(y1) << 16);
      pkA.y = (unsigned int)f2b(y2) | ((unsigned int)f2b(y3) << 16);
      pkB.x = (unsigned int)f2b(y4) | ((unsigned int)f2b(y5) << 16);
      pkB.y = (unsigned int)f2b(y6) | ((unsigned int)f2b(y7) << 16);
      const int r = w*32 + p*4 + q;
      *(uint2*)&xs[r*68 + c*2] = pkA;
      *(uint2*)&xs[r*68 + 32 + c*2] = pkB;
    }
  }

  s16x8 bw[4][4];
  #pragma unroll
  for (int t = 0; t < 4; ++t)
    #pragma unroll
    for (int kb = 0; kb < 4; ++kb)
      bw[kb][t] = *(const s16x8*)(wkb + (t*16 + m16)*128 + kb*32 + q*8);

  __syncthreads();

  const f32x4 zf = {0.f, 0.f, 0.f, 0.f};

  #pragma unroll
  for (int mi = 0; mi < 2; ++mi){
    int n0 = (w*2 + mi) * 16;
    f32x4 acc[4];
    #pragma unroll
    for (int t = 0; t < 4; ++t) acc[t] = zf;
    #pragma unroll
    for (int kb = 0; kb < 4; ++kb){
      s16x8 af = *(const s16x8*)((const unsigned short*)(xs + (n0 + m16)*68) + kb*32 + q*8);
      #pragma unroll
      for (int t = 0; t < 4; ++t)
        acc[t] = mfma16(af, bw[kb][t], acc[t]);
    }
    #pragma unroll
    for (int t = 0; t < 4; ++t){
      int h = t*16 + m16;
      #pragma unroll
      for (int rr = 0; rr < 4; ++rr){
        long n = rowg0 + n0 + q*4 + rr;
        kg[n*64 + h] = f2b(acc[t][rr]);
      }
    }
  }

  #pragma unroll
  for (int t = 0; t < 4; ++t)
    #pragma unroll
    for (int kb = 0; kb < 4; ++kb)
      bw[kb][t] = *(const s16x8*)(wvb + (t*16 + m16)*128 + kb*32 + q*8);

  #pragma unroll
  for (int mi = 0; mi < 2; ++mi){
    int n0 = (w*2 + mi) * 16;
    f32x4 acc[4];
    #pragma unroll
    for (int t = 0; t < 4; ++t) acc[t] = zf;
    #pragma unroll
    for (int kb = 0; kb < 4; ++kb){
      s16x8 af = *(const s16x8*)((const unsigned short*)(xs + (n0 + m16)*68) + kb*32 + q*8);
      #pragma unroll
      for (int t = 0; t < 4; ++t)
        acc[t] = mfma16(af, bw[kb][t], acc[t]);
    }
    #pragma unroll
    for (int t = 0; t < 4; ++t){
      int h = t*16 + m16;
      unsigned int p0 = (unsigned int)f2b(acc[t][0]) | ((unsigned int)f2b(acc[t][1]) << 16);
      unsigned int p1 = (unsigned int)f2b(acc[t][2]) | ((unsigned int)f2b(acc[t][3]) << 16);
      uint2 pv; pv.x = p0; pv.y = p1;
      long off = ((long)b*64 + h)*4096 + nbase + n0 + q*4;
      *(uint2*)(vt + off) = pv;
    }
  }
}

// ---------------------------------------------------------------------------
// K3: [GRU prologue (it>0, sums 16 U/S tile-partials)] + attention.
// BYTE-IDENTICAL to the verified round-7 k_attn3 (201.9us, absmax 0.0390625).
// ---------------------------------------------------------------------------
__global__ __launch_bounds__(256) void k_attn3(
    const unsigned short* __restrict__ kg,
    const unsigned short* __restrict__ vt,
    const unsigned short* __restrict__ qws,   // it==0 only
    const unsigned short* __restrict__ wall,  // packed [wih|whh|w1|w2|wq] bf16
    const float* __restrict__ bih, const float* __restrict__ bhh,
    const float* __restrict__ b1p, const float* __restrict__ b2p,
    const float* __restrict__ gmlp, const float* __restrict__ bmlp,
    const float* __restrict__ gsl, const float* __restrict__ bsl,
    const float* __restrict__ Up_in, const float* __restrict__ Sp_in,
    float* __restrict__ Up_out, float* __restrict__ Sp_out,
    const float* __restrict__ slin, float* __restrict__ slout,
    int it)
{
  __shared__ float sc[256*17];
  __shared__ unsigned short aT[16*264];
  __shared__ unsigned short ut[16*72], ht[16*72], st[16*72], hid[16*136];
  __shared__ unsigned short qloc[16*72];
  __shared__ __align__(16) float redS[16][4];
  __shared__ __align__(16) float redQ[16][4];
  __shared__ __align__(16) float redS2[16][4];
  __shared__ __align__(16) float redQ2[16][4];

  const int tid = threadIdx.x;
  const int w = tid >> 6, ln = tid & 63;
  const int m16 = ln & 15, q = ln >> 4;
  const int b = blockIdx.x >> 4;
  const int tile = blockIdx.x & 15;
  const int nbase = tile << 8;

  // ---- prefetch attention operands (independent of prologue) ----
  s16x8 afp[4];
  #pragma unroll
  for (int mi = 0; mi < 4; ++mi){
    int n0 = (w*4 + mi)*16;
    afp[mi] = *(const s16x8*)(kg + ((long)b*4096 + nbase + n0 + m16)*64 + q*8);
  }
  s16x8 afp2[4];
  #pragma unroll
  for (int mi = 0; mi < 4; ++mi){
    int n0 = (w*4 + mi)*16;
    afp2[mi] = *(const s16x8*)(kg + ((long)b*4096 + nbase + n0 + m16)*64 + 32 + q*8);
  }
  s16x8 vtp[8];
  #pragma unroll
  for (int ks = 0; ks < 8; ++ks)
    vtp[ks] = *(const s16x8*)(vt + ((long)b*64 + w*16 + m16)*4096 + nbase + ks*32 + q*8);

  for (int i = tid; i < 8*264; i += 256) aT[8*264 + i] = 0;  // aT slot-pad rows
  if (tid < 128){                                            // qloc pad rows 8..15
    int row = 8 + (tid >> 4), c = (tid & 15)*4;
    ushort4 z4 = {0,0,0,0};
    *(ushort4*)&qloc[row*72 + c] = z4;
  }

  if (it == 0){
    if (tid < 128){
      int row = tid >> 4, c = (tid & 15)*4;
      *(ushort4*)&qloc[row*72 + c] = *(const ushort4*)(qws + (b*16 + row)*64 + c);
    }
  } else {
    // ---- redundant GRU+LN+MLP+LN_sl+q for batch pair (b&~1, b|1) ----
    const int r0 = (b >> 1) * 16;
    const int cw = w*16 + m16;
    const unsigned short* wihb = wall;
    const unsigned short* whhb = wall + 12288;
    const unsigned short* w1b  = wall + 24576;
    const unsigned short* w2b  = wall + 32768;
    const unsigned short* wqb  = wall + 40960;

    #pragma unroll
    for (int p = 0; p < 4; ++p){
      int row = p*4 + w;
      int g = r0 + row;
      int bb = g >> 3, sl = g & 7;
      const float* up  = Up_in + ((bb*16)*8 + sl)*64 + ln;
      const float* spp = Sp_in + (bb*16)*8 + sl;
      float usum = 0.f, ssum = 0.f;
      #pragma unroll
      for (int t = 0; t < 16; ++t){
        usum += up[t*512];
        ssum += spp[t*8];
      }
      ut[row*72 + ln] = f2b(usum / ssum);
      ht[row*72 + ln] = f2b(slin[g*64 + ln]);
    }
    __syncthreads();

    f32x4 axr = {0,0,0,0}, axz = {0,0,0,0}, axn = {0,0,0,0};
    f32x4 ahr = {0,0,0,0}, ahz = {0,0,0,0}, ahn = {0,0,0,0};
    #pragma unroll
    for (int ks = 0; ks < 2; ++ks){
      s16x8 au = *(const s16x8*)(ut + m16*72 + ks*32 + q*8);
      s16x8 ah = *(const s16x8*)(ht + m16*72 + ks*32 + q*8);
      axr = mfma16(au, *(const s16x8*)(wihb + (      cw)*64 + ks*32 + q*8), axr);
      axz = mfma16(au, *(const s16x8*)(wihb + ( 64 + cw)*64 + ks*32 + q*8), axz);
      axn = mfma16(au, *(const s16x8*)(wihb + (128 + cw)*64 + ks*32 + q*8), axn);
      ahr = mfma16(ah, *(const s16x8*)(whhb + (      cw)*64 + ks*32 + q*8), ahr);
      ahz = mfma16(ah, *(const s16x8*)(whhb + ( 64 + cw)*64 + ks*32 + q*8), ahz);
      ahn = mfma16(ah, *(const s16x8*)(whhb + (128 + cw)*64 + ks*32 + q*8), ahn);
    }
    const float bxr = bih[cw], bxz = bih[64+cw], bxn = bih[128+cw];
    const float bhr = bhh[cw], bhz = bhh[64+cw], bhn = bhh[128+cw];
    float sp[4];
    #pragma unroll
    for (int rr = 0; rr < 4; ++rr){
      float xr = axr[rr] + bxr, xz = axz[rr] + bxz, xnv = axn[rr] + bxn;
      float hr = ahr[rr] + bhr, hz = ahz[rr] + bhz, hn = ahn[rr] + bhn;
      float rg = 1.f / (1.f + expf(-(xr + hr)));
      float zg = 1.f / (1.f + expf(-(xz + hz)));
      float ng = tanhf(xnv + rg*hn);
      float hv = b2f(ht[(q*4 + rr)*72 + cw]);
      sp[rr] = (1.f - zg)*ng + zg*hv;
    }

    float s1[4], s2[4];
    #pragma unroll
    for (int rr = 0; rr < 4; ++rr){
      s1[rr] = rsum16(sp[rr]);
      s2[rr] = rsum16(sp[rr]*sp[rr]);
    }
    if (m16 == 0){
      #pragma unroll
      for (int rr = 0; rr < 4; ++rr){ redS[q*4+rr][w] = s1[rr]; redQ[q*4+rr][w] = s2[rr]; }
    }
    __syncthreads();
    float sl_[4];
    {
      const float gm = gmlp[cw], bm = bmlp[cw];
      #pragma unroll
      for (int rr = 0; rr < 4; ++rr){
        f32x4 aS = *(const f32x4*)redS[q*4+rr];
        f32x4 aQ = *(const f32x4*)redQ[q*4+rr];
        float tS = aS[0]+aS[1]+aS[2]+aS[3];
        float tQ = aQ[0]+aQ[1]+aQ[2]+aQ[3];
        float mean = tS*(1.f/64.f);
        float var  = tQ*(1.f/64.f) - mean*mean;
        float rs = rsqrtf(var + 1e-5f);
        sl_[rr] = (sp[rr] - mean)*rs*gm + bm;
        st[(q*4+rr)*72 + cw] = f2b(sl_[rr]);
      }
    }
    __syncthreads();

    // mlp1 (64->128) + relu
    #pragma unroll
    for (int t2 = 0; t2 < 2; ++t2){
      int nt = w*2 + t2;
      int col = nt*16 + m16;
      f32x4 acc = {0,0,0,0};
      #pragma unroll
      for (int ks = 0; ks < 2; ++ks){
        s16x8 a = *(const s16x8*)(st + m16*72 + ks*32 + q*8);
        acc = mfma16(a, *(const s16x8*)(w1b + col*64 + ks*32 + q*8), acc);
      }
      float bb = b1p[col];
      #pragma unroll
      for (int rr = 0; rr < 4; ++rr)
        hid[(q*4+rr)*136 + col] = f2b(fmaxf(acc[rr] + bb, 0.f));
    }
    __syncthreads();

    // mlp2 (128->64) + residual
    float snew[4];
    {
      f32x4 acc = {0,0,0,0};
      #pragma unroll
      for (int ks = 0; ks < 4; ++ks){
        s16x8 a = *(const s16x8*)(hid + m16*136 + ks*32 + q*8);
        acc = mfma16(a, *(const s16x8*)(w2b + cw*128 + ks*32 + q*8), acc);
      }
      float bb = b2p[cw];
      #pragma unroll
      for (int rr = 0; rr < 4; ++rr){
        snew[rr] = sl_[rr] + acc[rr] + bb;
        if ((blockIdx.x & 31) == 0)
          slout[(r0 + q*4 + rr)*64 + cw] = snew[rr];   // one gate block per pair
      }
    }

    // LN_sl(snew) -> q into qloc (own redS2/redQ2: no pre-write barrier)
    #pragma unroll
    for (int rr = 0; rr < 4; ++rr){
      s1[rr] = rsum16(snew[rr]);
      s2[rr] = rsum16(snew[rr]*snew[rr]);
    }
    if (m16 == 0){
      #pragma unroll
      for (int rr = 0; rr < 4; ++rr){ redS2[q*4+rr][w] = s1[rr]; redQ2[q*4+rr][w] = s2[rr]; }
    }
    __syncthreads();
    {
      const float gs = gsl[cw], bs = bsl[cw];
      #pragma unroll
      for (int rr = 0; rr < 4; ++rr){
        f32x4 aS = *(const f32x4*)redS2[q*4+rr];
        f32x4 aQ = *(const f32x4*)redQ2[q*4+rr];
        float tS = aS[0]+aS[1]+aS[2]+aS[3];
        float tQ = aQ[0]+aQ[1]+aQ[2]+aQ[3];
        float mean = tS*(1.f/64.f);
        float var  = tQ*(1.f/64.f) - mean*mean;
        float rs = rsqrtf(var + 1e-5f);
        float sq = (snew[rr] - mean)*rs*gs + bs;
        st[(q*4+rr)*72 + cw] = f2b(sq);
      }
    }
    __syncthreads();
    {
      f32x4 acc = {0,0,0,0};
      #pragma unroll
      for (int ks = 0; ks < 2; ++ks){
        s16x8 a = *(const s16x8*)(st + m16*72 + ks*32 + q*8);
        acc = mfma16(a, *(const s16x8*)(wqb + cw*64 + ks*32 + q*8), acc);
      }
      #pragma unroll
      for (int rr = 0; rr < 4; ++rr){
        int rloc = q*4 + rr;
        if ((rloc >> 3) == (b & 1))
          qloc[(rloc & 7)*72 + cw] = f2b(acc[rr] * 0.125f);
      }
    }
  }
  __syncthreads();

  // ---- attention (kg already in afp/afp2 registers) ----
  s16x8 bq[2];
  #pragma unroll
  for (int ks = 0; ks < 2; ++ks)
    bq[ks] = *(const s16x8*)(qloc + m16*72 + ks*32 + q*8);

  #pragma unroll
  for (int mi = 0; mi < 4; ++mi){
    int n0 = (w*4 + mi)*16;
    f32x4 acc = {0.f, 0.f, 0.f, 0.f};
    acc = mfma16(afp[mi],  bq[0], acc);
    acc = mfma16(afp2[mi], bq[1], acc);
    #pragma unroll
    for (int rr = 0; rr < 4; ++rr)
      sc[(n0 + q*4 + rr)*17 + m16] = acc[rr];
  }
  __syncthreads();

  {
    int r = tid;
    float a8[8];
    float mx = -1e30f;
    #pragma unroll
    for (int j = 0; j < 8; ++j){ a8[j] = sc[r*17 + j]; mx = fmaxf(mx, a8[j]); }
    float ssum = 0.f;
    #pragma unroll
    for (int j = 0; j < 8; ++j){ a8[j] = expf(a8[j] - mx); ssum += a8[j]; }
    float inv = 1.f/ssum;
    #pragma unroll
    for (int j = 0; j < 8; ++j)
      aT[j*264 + r] = f2b(a8[j]*inv + 1e-8f);
  }
  __syncthreads();

  {  // S tile-partials: rsum16 + one xor16 (reduce over 32 lanes)
    int j = tid >> 5, c = tid & 31;
    float p = 0.f;
    #pragma unroll
    for (int i = 0; i < 8; ++i) p += b2f(aT[j*264 + c + 32*i]);
    p = rsum16(p);
    p += __shfl_xor(p, 16);
    if ((tid & 31) == 0) Sp_out[(b*16 + tile)*8 + j] = p;
  }

  {  // U tile-partials: wave w handles h-tile nt = w; vt already in vtp regs
    f32x4 acc = {0.f, 0.f, 0.f, 0.f};
    #pragma unroll
    for (int ks = 0; ks < 8; ++ks){
      s16x8 af = *(const s16x8*)(aT + m16*264 + ks*32 + q*8);
      acc = mfma16(af, vtp[ks], acc);
    }
    float* ub = Up_out + ((b*16 + tile)*8)*64 + w*16 + m16;
    #pragma unroll
    for (int rr = 0; rr < 4; ++rr){
      int slot = q*4 + rr;
      if (slot < 8)
        ub[slot*64] = acc[rr];
    }
  }
}

// ---------------------------------------------------------------------------
// K4: final GRU + LN_mlp + MLP(+residual) -> outp; sums the 16 tile-partials.
// UNCHANGED from round 7.
// ---------------------------------------------------------------------------
__global__ __launch_bounds__(256) void k_gru2(
    const float* __restrict__ Up, const float* __restrict__ Sp,
    const float* __restrict__ slots,
    const float* __restrict__ wih, const float* __restrict__ whh,
    const float* __restrict__ bih, const float* __restrict__ bhh,
    const float* __restrict__ w1, const float* __restrict__ b1p,
    const float* __restrict__ w2, const float* __restrict__ b2p,
    const float* __restrict__ gmlp, const float* __restrict__ bmlp,
    float* __restrict__ outp)
{
  __shared__ unsigned short ut[16*72], ht[16*72], st[16*72], hid[16*136];
  __shared__ __align__(16) float redS[16][4];
  __shared__ __align__(16) float redQ[16][4];
  const int tid = threadIdx.x;
  const int w = tid >> 6, ln = tid & 63;
  const int m16 = ln & 15, q = ln >> 4;
  const int r0 = blockIdx.x * 16;
  const int cw = w*16 + m16;

  #pragma unroll
  for (int p = 0; p < 4; ++p){
    int row = p*4 + w;
    int g = r0 + row;
    int bb = g >> 3, sl = g & 7;
    const float* up  = Up + ((bb*16)*8 + sl)*64 + ln;
    const float* spp = Sp + (bb*16)*8 + sl;
    float usum = 0.f, ssum = 0.f;
    #pragma unroll
    for (int t = 0; t < 16; ++t){
      usum += up[t*512];
      ssum += spp[t*8];
    }
    ut[row*72 + ln] = f2b(usum / ssum);
    ht[row*72 + ln] = f2b(slots[g*64 + ln]);
  }
  __syncthreads();

  f32x4 axr = {0,0,0,0}, axz = {0,0,0,0}, axn = {0,0,0,0};
  f32x4 ahr = {0,0,0,0}, ahz = {0,0,0,0}, ahn = {0,0,0,0};
  #pragma unroll
  for (int ks = 0; ks < 2; ++ks){
    s16x8 au = *(const s16x8*)(ut + m16*72 + ks*32 + q*8);
    s16x8 ah = *(const s16x8*)(ht + m16*72 + ks*32 + q*8);
    axr = mfma16(au, ld8f(wih + (      cw)*64 + ks*32 + q*8), axr);
    axz = mfma16(au, ld8f(wih + ( 64 + cw)*64 + ks*32 + q*8), axz);
    axn = mfma16(au, ld8f(wih + (128 + cw)*64 + ks*32 + q*8), axn);
    ahr = mfma16(ah, ld8f(whh + (      cw)*64 + ks*32 + q*8), ahr);
    ahz = mfma16(ah, ld8f(whh + ( 64 + cw)*64 + ks*32 + q*8), ahz);
    ahn = mfma16(ah, ld8f(whh + (128 + cw)*64 + ks*32 + q*8), ahn);
  }
  const float bxr = bih[cw], bxz = bih[64+cw], bxn = bih[128+cw];
  const float bhr = bhh[cw], bhz = bhh[64+cw], bhn = bhh[128+cw];
  float sp[4];
  #pragma unroll
  for (int rr = 0; rr < 4; ++rr){
    float xr = axr[rr] + bxr, xz = axz[rr] + bxz, xnv = axn[rr] + bxn;
    float hr = ahr[rr] + bhr, hz = ahz[rr] + bhz, hn = ahn[rr] + bhn;
    float rg = 1.f / (1.f + expf(-(xr + hr)));
    float zg = 1.f / (1.f + expf(-(xz + hz)));
    float ng = tanhf(xnv + rg*hn);
    float hv = b2f(ht[(q*4 + rr)*72 + cw]);
    sp[rr] = (1.f - zg)*ng + zg*hv;
  }

  float s1[4], s2[4];
  #pragma unroll
  for (int rr = 0; rr < 4; ++rr){
    s1[rr] = rsum16(sp[rr]);
    s2[rr] = rsum16(sp[rr]*sp[rr]);
  }
  if (m16 == 0){
    #pragma unroll
    for (int rr = 0; rr < 4; ++rr){ redS[q*4+rr][w] = s1[rr]; redQ[q*4+rr][w] = s2[rr]; }
  }
  __syncthreads();
  float sl_[4];
  {
    const float gm = gmlp[cw], bm = bmlp[cw];
    #pragma unroll
    for (int rr = 0; rr < 4; ++rr){
      f32x4 aS = *(const f32x4*)redS[q*4+rr];
      f32x4 aQ = *(const f32x4*)redQ[q*4+rr];
      float tS = aS[0]+aS[1]+aS[2]+aS[3];
      float tQ = aQ[0]+aQ[1]+aQ[2]+aQ[3];
      float mean = tS*(1.f/64.f);
      float var  = tQ*(1.f/64.f) - mean*mean;
      float rs = rsqrtf(var + 1e-5f);
      sl_[rr] = (sp[rr] - mean)*rs*gm + bm;
      st[(q*4+rr)*72 + cw] = f2b(sl_[rr]);
    }
  }
  __syncthreads();

  #pragma unroll
  for (int t2 = 0; t2 < 2; ++t2){
    int nt = w*2 + t2;
    int col = nt*16 + m16;
    f32x4 acc = {0,0,0,0};
    #pragma unroll
    for (int ks = 0; ks < 2; ++ks){
      s16x8 a = *(const s16x8*)(st + m16*72 + ks*32 + q*8);
      acc = mfma16(a, ld8f(w1 + col*64 + ks*32 + q*8), acc);
    }
    float bb = b1p[col];
    #pragma unroll
    for (int rr = 0; rr < 4; ++rr)
      hid[(q*4+rr)*136 + col] = f2b(fmaxf(acc[rr] + bb, 0.f));
  }
  __syncthreads();

  {
    f32x4 acc = {0,0,0,0};
    #pragma unroll
    for (int ks = 0; ks < 4; ++ks){
      s16x8 a = *(const s16x8*)(hid + m16*136 + ks*32 + q*8);
      acc = mfma16(a, ld8f(w2 + cw*128 + ks*32 + q*8), acc);
    }
    float bb = b2p[cw];
    #pragma unroll
    for (int rr = 0; rr < 4; ++rr){
      int row = r0 + q*4 + rr;
      outp[row*64 + cw] = sl_[rr] + acc[rr] + bb;
    }
  }
}

// ---------------------------------------------------------------------------
extern "C" void kernel_launch(void* const* d_in, const int* in_sizes, int n_in,
                              void* d_out, int out_size, void* d_ws, size_t ws_size,
                              hipStream_t stream)
{
  const float* x    = (const float*)d_in[0];
  const float* noise= (const float*)d_in[1];
  const float* Wq   = (const float*)d_in[2];
  const float* Wk   = (const float*)d_in[3];
  const float* Wv   = (const float*)d_in[4];
  const float* ling = (const float*)d_in[5];
  const float* linb = (const float*)d_in[6];
  const float* gsl  = (const float*)d_in[7];
  const float* bsl  = (const float*)d_in[8];
  const float* gmlp = (const float*)d_in[9];
  const float* bmlp = (const float*)d_in[10];
  const float* wih  = (const float*)d_in[11];
  const float* whh  = (const float*)d_in[12];
  const float* bih  = (const float*)d_in[13];
  const float* bhh  = (const float*)d_in[14];
  const float* w1   = (const float*)d_in[15];
  const float* b1p  = (const float*)d_in[16];
  const float* w2   = (const float*)d_in[17];
  const float* b2p  = (const float*)d_in[18];
  const float* mu   = (const float*)d_in[19];
  const float* lsg  = (const float*)d_in[20];

  char* ws = (char*)d_ws;
  unsigned short* kg   = (unsigned short*)(ws);              // 16 MiB
  unsigned short* vt   = (unsigned short*)(ws + 16777216);   // 16 MiB
  char* base = ws + 33554432;
  unsigned short* qws  = (unsigned short*)(base);            // 64 KiB
  float* slotsA        = (float*)(base + 65536);             // 64 KiB
  float* slotsB        = (float*)(base + 131072);
  float* slotsC        = (float*)(base + 196608);
  float* UA            = (float*)(base + 262144);            // 1 MiB partials
  float* UB            = (float*)(base + 1310720);           // 1 MiB
  float* SA            = (float*)(base + 2359296);           // 16 KiB
  float* SB            = (float*)(base + 2375680);           // 16 KiB
  unsigned short* wkb  = (unsigned short*)(base + 2392064);  // 16 KiB
  unsigned short* wvb  = (unsigned short*)(base + 2408448);  // 16 KiB
  unsigned short* wall = (unsigned short*)(base + 2424832);  // 88 KiB packed weights
  float* outp          = (float*)d_out;

  hipLaunchKernelGGL(k_wpack, dim3(60), dim3(256), 0, stream,
                     Wk, Wv, wih, whh, w1, w2, Wq, wkb, wvb, wall);
  hipLaunchKernelGGL(k_lnkv7, dim3(1040), dim3(256), 0, stream,
                     x, wkb, wvb, ling, linb, kg, vt,
                     noise, mu, lsg, gsl, bsl, Wq, slotsA, qws);
  // it=0: q from qws; write iter-0 partials into UA/SA
  hipLaunchKernelGGL(k_attn3, dim3(512), dim3(256), 0, stream,
                     kg, vt, qws, wall, bih, bhh, b1p, b2p, gmlp, bmlp, gsl, bsl,
                     UA, SA, UA, SA, slotsA, slotsA, 0);
  // it=1: gru(sum UA/SA, slotsA)->slotsB + q; write iter-1 partials into UB/SB
  hipLaunchKernelGGL(k_attn3, dim3(512), dim3(256), 0, stream,
                     kg, vt, qws, wall, bih, bhh, b1p, b2p, gmlp, bmlp, gsl, bsl,
                     UA, SA, UB, SB, slotsA, slotsB, 1);
  // it=2: gru(sum UB/SB, slotsB)->slotsC + q; write iter-2 partials into UA/SA
  hipLaunchKernelGGL(k_attn3, dim3(512), dim3(256), 0, stream,
                     kg, vt, qws, wall, bih, bhh, b1p, b2p, gmlp, bmlp, gsl, bsl,
                     UB, SB, UA, SA, slotsB, slotsC, 2);
  // final gru(sum UA/SA, slotsC) -> outp
  hipLaunchKernelGGL(k_gru2, dim3(16), dim3(256), 0, stream, UA, SA, slotsC,
                     wih, whh, bih, bhh, w1, b1p, w2, b2p, gmlp, bmlp, outp);
  (void)in_sizes; (void)n_in; (void)out_size; (void)ws_size;
}

// Round 12
// 200.329 us; speedup vs baseline: 2.4231x; 1.0053x over previous
//
#include <hip/hip_runtime.h>

typedef __attribute__((ext_vector_type(8))) short s16x8;
typedef __attribute__((ext_vector_type(4))) float f32x4;

#define DEV static __device__ __forceinline__

DEV float b2f(unsigned short u){
  unsigned int i = ((unsigned int)u) << 16;
  float f; __builtin_memcpy(&f, &i, 4); return f;
}
DEV unsigned short f2b(float f){
  unsigned int i; __builtin_memcpy(&i, &f, 4);
  i = i + 0x7fffu + ((i >> 16) & 1u);
  return (unsigned short)(i >> 16);
}
DEV f32x4 mfma16(s16x8 a, s16x8 b, f32x4 c){
  return __builtin_amdgcn_mfma_f32_16x16x32_bf16(a, b, c, 0, 0, 0);
}
// load 8 consecutive f32 (32B-aligned) -> bf16 A/B fragment
DEV s16x8 ld8f(const float* p){
  const float4* q4 = (const float4*)p;
  float4 a = q4[0], b = q4[1];
  s16x8 r;
  r[0]=(short)f2b(a.x); r[1]=(short)f2b(a.y); r[2]=(short)f2b(a.z); r[3]=(short)f2b(a.w);
  r[4]=(short)f2b(b.x); r[5]=(short)f2b(b.y); r[6]=(short)f2b(b.z); r[7]=(short)f2b(b.w);
  return r;
}

// DPP-based 16-lane all-reduce sum
template<int C> DEV float dpp_addstep(float x){
  int y = __builtin_amdgcn_update_dpp(0, __builtin_bit_cast(int, x), C, 0xF, 0xF, true);
  return x + __builtin_bit_cast(float, y);
}
DEV float rsum16(float v){
  v = dpp_addstep<0xB1>(v);   // quad_perm xor1
  v = dpp_addstep<0x4E>(v);   // quad_perm xor2
  v = dpp_addstep<0x141>(v);  // row_half_mirror
  v = dpp_addstep<0x140>(v);  // row_mirror
  return v;
}

// ---------------------------------------------------------------------------
// K0: one-shot pack of ALL weights -> bf16. (Round-9 lesson: do NOT inline
// this into k_lnkv -- conversion code between barrier and stores breaks the
// inter-wave store timing the vt write-merge depends on: 33->93MB writes.)
// wall layout (elements): wih@0 whh@12288 w1@24576 w2@32768 wq@40960.
// ---------------------------------------------------------------------------
__global__ __launch_bounds__(256) void k_wpack(
    const float* __restrict__ Wk, const float* __restrict__ Wv,
    const float* __restrict__ wih, const float* __restrict__ whh,
    const float* __restrict__ w1, const float* __restrict__ w2,
    const float* __restrict__ Wq,
    unsigned short* __restrict__ wkb, unsigned short* __restrict__ wvb,
    unsigned short* __restrict__ wall)
{
  int t = blockIdx.x * 256 + threadIdx.x;
  int off = t * 4;
  const float* src; unsigned short* dst;
  if      (off <  8192){ src = Wk  + off;         dst = wkb  + off; }
  else if (off < 16384){ src = Wv  + off -  8192; dst = wvb  + off - 8192; }
  else if (off < 28672){ src = wih + off - 16384; dst = wall + off - 16384; }
  else if (off < 40960){ src = whh + off - 28672; dst = wall + off - 16384; }
  else if (off < 49152){ src = w1  + off - 40960; dst = wall + off - 16384; }
  else if (off < 57344){ src = w2  + off - 49152; dst = wall + off - 16384; }
  else                 { src = Wq  + off - 57344; dst = wall + off - 16384; }
  float4 v = *(const float4*)src;
  ushort4 o;
  o.x = f2b(v.x); o.y = f2b(v.y); o.z = f2b(v.z); o.w = f2b(v.w);
  *(ushort4*)dst = o;
}

// ---------------------------------------------------------------------------
// K1: LN(x) -> k (plain [b][n][h] bf16), v^T ([b][h][n] bf16). FROZEN
// (round-7/10 verified: FETCH 33MB / WRITE 33MB; prefetch-depth null =>
// structural floor).
// INVARIANT: each wave covers TWO adjacent 16-col vt tiles AND no extra code
// between the barrier and the stores.
// ---------------------------------------------------------------------------
__global__ __launch_bounds__(256, 4) void k_lnkv7(
    const float* __restrict__ x,
    const unsigned short* __restrict__ wkb,
    const unsigned short* __restrict__ wvb,
    const float* __restrict__ lg,
    const float* __restrict__ lb,
    unsigned short* __restrict__ kg,
    unsigned short* __restrict__ vt,
    // init tail-block args
    const float* __restrict__ noise,
    const float* __restrict__ mu,
    const float* __restrict__ lsg,
    const float* __restrict__ gsl,
    const float* __restrict__ bsl,
    const float* __restrict__ Wq,
    float* __restrict__ slots,
    unsigned short* __restrict__ qws)
{
  __shared__ __align__(16) unsigned int xs[128 * 68];
  const int tid = threadIdx.x;
  const int w = tid >> 6, ln = tid & 63;
  const int m16 = ln & 15, q = ln >> 4;

  if (blockIdx.x >= 1024){
    // ---------------- slot-init path (16 tail blocks) ----------------
    unsigned short* st = (unsigned short*)xs;
    float (*redS)[4] = (float(*)[4])((char*)xs + 2304);
    float (*redQ)[4] = (float(*)[4])((char*)xs + 2560);
    const int bi = blockIdx.x - 1024;
    const int r0 = bi * 16;
    const int cw = w*16 + m16;

    float sl[4], s1[4], s2[4];
    #pragma unroll
    for (int rr = 0; rr < 4; ++rr){
      int row = r0 + q*4 + rr;
      int k = row & 7;
      float v = mu[k*64 + cw] + (log1pf(expf(lsg[k*64 + cw])) + 1e-5f) * noise[row*64 + cw];
      sl[rr] = v;
      slots[row*64 + cw] = v;
      s1[rr] = rsum16(v);
      s2[rr] = rsum16(v*v);
    }
    if (m16 == 0){
      #pragma unroll
      for (int rr = 0; rr < 4; ++rr){ redS[q*4+rr][w] = s1[rr]; redQ[q*4+rr][w] = s2[rr]; }
    }
    __syncthreads();
    {
      const float gs = gsl[cw], bs = bsl[cw];
      #pragma unroll
      for (int rr = 0; rr < 4; ++rr){
        f32x4 aS = *(const f32x4*)redS[q*4+rr];
        f32x4 aQ = *(const f32x4*)redQ[q*4+rr];
        float tS = aS[0]+aS[1]+aS[2]+aS[3];
        float tQ = aQ[0]+aQ[1]+aQ[2]+aQ[3];
        float mean = tS*(1.f/64.f);
        float var  = tQ*(1.f/64.f) - mean*mean;
        float rs = rsqrtf(var + 1e-5f);
        float sq = (sl[rr] - mean)*rs*gs + bs;
        st[(q*4+rr)*72 + cw] = f2b(sq);
      }
    }
    __syncthreads();
    {
      f32x4 acc = {0,0,0,0};
      #pragma unroll
      for (int ks = 0; ks < 2; ++ks){
        s16x8 a = *(const s16x8*)(st + m16*72 + ks*32 + q*8);
        acc = mfma16(a, ld8f(Wq + cw*64 + ks*32 + q*8), acc);
      }
      #pragma unroll
      for (int rr = 0; rr < 4; ++rr){
        int row = r0 + q*4 + rr;
        int bb_ = row >> 3, kk = row & 7;
        qws[(bb_*16 + kk)*64 + cw] = f2b(acc[rr] * 0.125f);
      }
      int b0 = bi * 2;
      ((unsigned int*)(qws + (b0*16 + 8)*64))[tid] = 0u;
      ((unsigned int*)(qws + ((b0+1)*16 + 8)*64))[tid] = 0u;
    }
    return;
  }

  // ---------------- LN + KV path (1024 blocks, 128 rows each) -------------
  const int b = blockIdx.x >> 5;
  const int nbase = (blockIdx.x & 31) << 7;
  const long rowg0 = (long)b * 4096 + nbase;

  {
    const int c = m16;
    const float4 gA = *(const float4*)(lg + c*4);
    const float4 gB = *(const float4*)(lg + 64 + c*4);
    const float4 bA = *(const float4*)(lb + c*4);
    const float4 bB = *(const float4*)(lb + 64 + c*4);
    const float* base = x + (rowg0 + w*32 + q)*128;

    float4 va[4], vb[4];
    #pragma unroll
    for (int i = 0; i < 3; ++i){
      va[i] = *(const float4*)(base + i*512 + c*4);
      vb[i] = *(const float4*)(base + i*512 + 64 + c*4);
    }
    #pragma unroll
    for (int p = 0; p < 8; ++p){
      const int cur = p & 3;
      if (p < 5){
        const int nxt = (p+3) & 3;
        va[nxt] = *(const float4*)(base + (p+3)*512 + c*4);
        vb[nxt] = *(const float4*)(base + (p+3)*512 + 64 + c*4);
      }
      float4 u = va[cur], t = vb[cur];
      float s1 = (u.x + u.y) + (u.z + u.w) + (t.x + t.y) + (t.z + t.w);
      float s2 = (u.x*u.x + u.y*u.y) + (u.z*u.z + u.w*u.w)
               + (t.x*t.x + t.y*t.y) + (t.z*t.z + t.w*t.w);
      s1 = rsum16(s1);
      s2 = rsum16(s2);
      float mean = s1 * (1.f/128.f);
      float var  = s2 * (1.f/128.f) - mean*mean;
      float rs = rsqrtf(var + 1e-5f);
      float y0 = (u.x - mean)*rs*gA.x + bA.x;
      float y1 = (u.y - mean)*rs*gA.y + bA.y;
      float y2 = (u.z - mean)*rs*gA.z + bA.z;
      float y3 = (u.w - mean)*rs*gA.w + bA.w;
      float y4 = (t.x - mean)*rs*gB.x + bB.x;
      float y5 = (t.y - mean)*rs*gB.y + bB.y;
      float y6 = (t.z - mean)*rs*gB.z + bB.z;
      float y7 = (t.w - mean)*rs*gB.w + bB.w;
      uint2 pkA, pkB;
      pkA.x = (unsigned int)f2b(y0) | ((unsigned int)f2b(y1) << 16);
      pkA.y = (unsigned int)f2b(y2) | ((unsigned int)f2b(y3) << 16);
      pkB.x = (unsigned int)f2b(y4) | ((unsigned int)f2b(y5) << 16);
      pkB.y = (unsigned int)f2b(y6) | ((unsigned int)f2b(y7) << 16);
      const int r = w*32 + p*4 + q;
      *(uint2*)&xs[r*68 + c*2] = pkA;
      *(uint2*)&xs[r*68 + 32 + c*2] = pkB;
    }
  }

  s16x8 bw[4][4];
  #pragma unroll
  for (int t = 0; t < 4; ++t)
    #pragma unroll
    for (int kb = 0; kb < 4; ++kb)
      bw[kb][t] = *(const s16x8*)(wkb + (t*16 + m16)*128 + kb*32 + q*8);

  __syncthreads();

  const f32x4 zf = {0.f, 0.f, 0.f, 0.f};

  #pragma unroll
  for (int mi = 0; mi < 2; ++mi){
    int n0 = (w*2 + mi) * 16;
    f32x4 acc[4];
    #pragma unroll
    for (int t = 0; t < 4; ++t) acc[t] = zf;
    #pragma unroll
    for (int kb = 0; kb < 4; ++kb){
      s16x8 af = *(const s16x8*)((const unsigned short*)(xs + (n0 + m16)*68) + kb*32 + q*8);
      #pragma unroll
      for (int t = 0; t < 4; ++t)
        acc[t] = mfma16(af, bw[kb][t], acc[t]);
    }
    #pragma unroll
    for (int t = 0; t < 4; ++t){
      int h = t*16 + m16;
      #pragma unroll
      for (int rr = 0; rr < 4; ++rr){
        long n = rowg0 + n0 + q*4 + rr;
        kg[n*64 + h] = f2b(acc[t][rr]);
      }
    }
  }

  #pragma unroll
  for (int t = 0; t < 4; ++t)
    #pragma unroll
    for (int kb = 0; kb < 4; ++kb)
      bw[kb][t] = *(const s16x8*)(wvb + (t*16 + m16)*128 + kb*32 + q*8);

  #pragma unroll
  for (int mi = 0; mi < 2; ++mi){
    int n0 = (w*2 + mi) * 16;
    f32x4 acc[4];
    #pragma unroll
    for (int t = 0; t < 4; ++t) acc[t] = zf;
    #pragma unroll
    for (int kb = 0; kb < 4; ++kb){
      s16x8 af = *(const s16x8*)((const unsigned short*)(xs + (n0 + m16)*68) + kb*32 + q*8);
      #pragma unroll
      for (int t = 0; t < 4; ++t)
        acc[t] = mfma16(af, bw[kb][t], acc[t]);
    }
    #pragma unroll
    for (int t = 0; t < 4; ++t){
      int h = t*16 + m16;
      unsigned int p0 = (unsigned int)f2b(acc[t][0]) | ((unsigned int)f2b(acc[t][1]) << 16);
      unsigned int p1 = (unsigned int)f2b(acc[t][2]) | ((unsigned int)f2b(acc[t][3]) << 16);
      uint2 pv; pv.x = p0; pv.y = p1;
      long off = ((long)b*64 + h)*4096 + nbase + n0 + q*4;
      *(uint2*)(vt + off) = pv;
    }
  }
}

// ---------------------------------------------------------------------------
// K3: [GRU prologue (it>0, sums 16 U/S tile-partials)] + attention.
// Round-11 change: XCD-aware block swizzle (T1) -- all 32 blocks of a
// batch-pair land on ONE XCD, so the prologue's shared reads (64KB U/S
// partials + 64KB slots + 88KB weights per pair) are fetched once per XCD
// instead of 8x. Pure bijective remap of blockIdx; body byte-identical to
// the verified round-7 k_attn3.
// ---------------------------------------------------------------------------
__global__ __launch_bounds__(256) void k_attn3(
    const unsigned short* __restrict__ kg,
    const unsigned short* __restrict__ vt,
    const unsigned short* __restrict__ qws,   // it==0 only
    const unsigned short* __restrict__ wall,  // packed [wih|whh|w1|w2|wq] bf16
    const float* __restrict__ bih, const float* __restrict__ bhh,
    const float* __restrict__ b1p, const float* __restrict__ b2p,
    const float* __restrict__ gmlp, const float* __restrict__ bmlp,
    const float* __restrict__ gsl, const float* __restrict__ bsl,
    const float* __restrict__ Up_in, const float* __restrict__ Sp_in,
    float* __restrict__ Up_out, float* __restrict__ Sp_out,
    const float* __restrict__ slin, float* __restrict__ slout,
    int it)
{
  __shared__ float sc[256*17];
  __shared__ unsigned short aT[16*264];
  __shared__ unsigned short ut[16*72], ht[16*72], st[16*72], hid[16*136];
  __shared__ unsigned short qloc[16*72];
  __shared__ __align__(16) float redS[16][4];
  __shared__ __align__(16) float redQ[16][4];
  __shared__ __align__(16) float redS2[16][4];
  __shared__ __align__(16) float redQ2[16][4];

  const int tid = threadIdx.x;
  const int w = tid >> 6, ln = tid & 63;
  const int m16 = ln & 15, q = ln >> 4;

  // XCD-aware swizzle: physical p -> logical lb such that each batch-pair's
  // 32 blocks share one XCD (p%8). 512 blocks / 8 XCDs = 64 slots/XCD =
  // 2 pairs/XCD. Bijection: lb = (xcd*2 + slot/32)*32 + slot%32.
  const int p_   = blockIdx.x;
  const int xcd  = p_ & 7;
  const int slot = p_ >> 3;
  const int lb   = ((xcd << 1) + (slot >> 5))*32 + (slot & 31);
  const int b = lb >> 4;
  const int tile = lb & 15;
  const int nbase = tile << 8;

  // ---- prefetch attention operands (independent of prologue) ----
  s16x8 afp[4];
  #pragma unroll
  for (int mi = 0; mi < 4; ++mi){
    int n0 = (w*4 + mi)*16;
    afp[mi] = *(const s16x8*)(kg + ((long)b*4096 + nbase + n0 + m16)*64 + q*8);
  }
  s16x8 afp2[4];
  #pragma unroll
  for (int mi = 0; mi < 4; ++mi){
    int n0 = (w*4 + mi)*16;
    afp2[mi] = *(const s16x8*)(kg + ((long)b*4096 + nbase + n0 + m16)*64 + 32 + q*8);
  }
  s16x8 vtp[8];
  #pragma unroll
  for (int ks = 0; ks < 8; ++ks)
    vtp[ks] = *(const s16x8*)(vt + ((long)b*64 + w*16 + m16)*4096 + nbase + ks*32 + q*8);

  for (int i = tid; i < 8*264; i += 256) aT[8*264 + i] = 0;  // aT slot-pad rows
  if (tid < 128){                                            // qloc pad rows 8..15
    int row = 8 + (tid >> 4), c = (tid & 15)*4;
    ushort4 z4 = {0,0,0,0};
    *(ushort4*)&qloc[row*72 + c] = z4;
  }

  if (it == 0){
    if (tid < 128){
      int row = tid >> 4, c = (tid & 15)*4;
      *(ushort4*)&qloc[row*72 + c] = *(const ushort4*)(qws + (b*16 + row)*64 + c);
    }
  } else {
    // ---- redundant GRU+LN+MLP+LN_sl+q for batch pair (b&~1, b|1) ----
    const int r0 = (b >> 1) * 16;
    const int cw = w*16 + m16;
    const unsigned short* wihb = wall;
    const unsigned short* whhb = wall + 12288;
    const unsigned short* w1b  = wall + 24576;
    const unsigned short* w2b  = wall + 32768;
    const unsigned short* wqb  = wall + 40960;

    #pragma unroll
    for (int p = 0; p < 4; ++p){
      int row = p*4 + w;
      int g = r0 + row;
      int bb = g >> 3, sl = g & 7;
      const float* up  = Up_in + ((bb*16)*8 + sl)*64 + ln;
      const float* spp = Sp_in + (bb*16)*8 + sl;
      float usum = 0.f, ssum = 0.f;
      #pragma unroll
      for (int t = 0; t < 16; ++t){
        usum += up[t*512];
        ssum += spp[t*8];
      }
      ut[row*72 + ln] = f2b(usum / ssum);
      ht[row*72 + ln] = f2b(slin[g*64 + ln]);
    }
    __syncthreads();

    f32x4 axr = {0,0,0,0}, axz = {0,0,0,0}, axn = {0,0,0,0};
    f32x4 ahr = {0,0,0,0}, ahz = {0,0,0,0}, ahn = {0,0,0,0};
    #pragma unroll
    for (int ks = 0; ks < 2; ++ks){
      s16x8 au = *(const s16x8*)(ut + m16*72 + ks*32 + q*8);
      s16x8 ah = *(const s16x8*)(ht + m16*72 + ks*32 + q*8);
      axr = mfma16(au, *(const s16x8*)(wihb + (      cw)*64 + ks*32 + q*8), axr);
      axz = mfma16(au, *(const s16x8*)(wihb + ( 64 + cw)*64 + ks*32 + q*8), axz);
      axn = mfma16(au, *(const s16x8*)(wihb + (128 + cw)*64 + ks*32 + q*8), axn);
      ahr = mfma16(ah, *(const s16x8*)(whhb + (      cw)*64 + ks*32 + q*8), ahr);
      ahz = mfma16(ah, *(const s16x8*)(whhb + ( 64 + cw)*64 + ks*32 + q*8), ahz);
      ahn = mfma16(ah, *(const s16x8*)(whhb + (128 + cw)*64 + ks*32 + q*8), ahn);
    }
    const float bxr = bih[cw], bxz = bih[64+cw], bxn = bih[128+cw];
    const float bhr = bhh[cw], bhz = bhh[64+cw], bhn = bhh[128+cw];
    float sp[4];
    #pragma unroll
    for (int rr = 0; rr < 4; ++rr){
      float xr = axr[rr] + bxr, xz = axz[rr] + bxz, xnv = axn[rr] + bxn;
      float hr = ahr[rr] + bhr, hz = ahz[rr] + bhz, hn = ahn[rr] + bhn;
      float rg = 1.f / (1.f + expf(-(xr + hr)));
      float zg = 1.f / (1.f + expf(-(xz + hz)));
      float ng = tanhf(xnv + rg*hn);
      float hv = b2f(ht[(q*4 + rr)*72 + cw]);
      sp[rr] = (1.f - zg)*ng + zg*hv;
    }

    float s1[4], s2[4];
    #pragma unroll
    for (int rr = 0; rr < 4; ++rr){
      s1[rr] = rsum16(sp[rr]);
      s2[rr] = rsum16(sp[rr]*sp[rr]);
    }
    if (m16 == 0){
      #pragma unroll
      for (int rr = 0; rr < 4; ++rr){ redS[q*4+rr][w] = s1[rr]; redQ[q*4+rr][w] = s2[rr]; }
    }
    __syncthreads();
    float sl_[4];
    {
      const float gm = gmlp[cw], bm = bmlp[cw];
      #pragma unroll
      for (int rr = 0; rr < 4; ++rr){
        f32x4 aS = *(const f32x4*)redS[q*4+rr];
        f32x4 aQ = *(const f32x4*)redQ[q*4+rr];
        float tS = aS[0]+aS[1]+aS[2]+aS[3];
        float tQ = aQ[0]+aQ[1]+aQ[2]+aQ[3];
        float mean = tS*(1.f/64.f);
        float var  = tQ*(1.f/64.f) - mean*mean;
        float rs = rsqrtf(var + 1e-5f);
        sl_[rr] = (sp[rr] - mean)*rs*gm + bm;
        st[(q*4+rr)*72 + cw] = f2b(sl_[rr]);
      }
    }
    __syncthreads();

    // mlp1 (64->128) + relu
    #pragma unroll
    for (int t2 = 0; t2 < 2; ++t2){
      int nt = w*2 + t2;
      int col = nt*16 + m16;
      f32x4 acc = {0,0,0,0};
      #pragma unroll
      for (int ks = 0; ks < 2; ++ks){
        s16x8 a = *(const s16x8*)(st + m16*72 + ks*32 + q*8);
        acc = mfma16(a, *(const s16x8*)(w1b + col*64 + ks*32 + q*8), acc);
      }
      float bb = b1p[col];
      #pragma unroll
      for (int rr = 0; rr < 4; ++rr)
        hid[(q*4+rr)*136 + col] = f2b(fmaxf(acc[rr] + bb, 0.f));
    }
    __syncthreads();

    // mlp2 (128->64) + residual
    float snew[4];
    {
      f32x4 acc = {0,0,0,0};
      #pragma unroll
      for (int ks = 0; ks < 4; ++ks){
        s16x8 a = *(const s16x8*)(hid + m16*136 + ks*32 + q*8);
        acc = mfma16(a, *(const s16x8*)(w2b + cw*128 + ks*32 + q*8), acc);
      }
      float bb = b2p[cw];
      #pragma unroll
      for (int rr = 0; rr < 4; ++rr){
        snew[rr] = sl_[rr] + acc[rr] + bb;
        if ((lb & 31) == 0)
          slout[(r0 + q*4 + rr)*64 + cw] = snew[rr];   // one gate block per pair
      }
    }

    // LN_sl(snew) -> q into qloc (own redS2/redQ2: no pre-write barrier)
    #pragma unroll
    for (int rr = 0; rr < 4; ++rr){
      s1[rr] = rsum16(snew[rr]);
      s2[rr] = rsum16(snew[rr]*snew[rr]);
    }
    if (m16 == 0){
      #pragma unroll
      for (int rr = 0; rr < 4; ++rr){ redS2[q*4+rr][w] = s1[rr]; redQ2[q*4+rr][w] = s2[rr]; }
    }
    __syncthreads();
    {
      const float gs = gsl[cw], bs = bsl[cw];
      #pragma unroll
      for (int rr = 0; rr < 4; ++rr){
        f32x4 aS = *(const f32x4*)redS2[q*4+rr];
        f32x4 aQ = *(const f32x4*)redQ2[q*4+rr];
        float tS = aS[0]+aS[1]+aS[2]+aS[3];
        float tQ = aQ[0]+aQ[1]+aQ[2]+aQ[3];
        float mean = tS*(1.f/64.f);
        float var  = tQ*(1.f/64.f) - mean*mean;
        float rs = rsqrtf(var + 1e-5f);
        float sq = (snew[rr] - mean)*rs*gs + bs;
        st[(q*4+rr)*72 + cw] = f2b(sq);
      }
    }
    __syncthreads();
    {
      f32x4 acc = {0,0,0,0};
      #pragma unroll
      for (int ks = 0; ks < 2; ++ks){
        s16x8 a = *(const s16x8*)(st + m16*72 + ks*32 + q*8);
        acc = mfma16(a, *(const s16x8*)(wqb + cw*64 + ks*32 + q*8), acc);
      }
      #pragma unroll
      for (int rr = 0; rr < 4; ++rr){
        int rloc = q*4 + rr;
        if ((rloc >> 3) == (b & 1))
          qloc[(rloc & 7)*72 + cw] = f2b(acc[rr] * 0.125f);
      }
    }
  }
  __syncthreads();

  // ---- attention (kg already in afp/afp2 registers) ----
  s16x8 bq[2];
  #pragma unroll
  for (int ks = 0; ks < 2; ++ks)
    bq[ks] = *(const s16x8*)(qloc + m16*72 + ks*32 + q*8);

  #pragma unroll
  for (int mi = 0; mi < 4; ++mi){
    int n0 = (w*4 + mi)*16;
    f32x4 acc = {0.f, 0.f, 0.f, 0.f};
    acc = mfma16(afp[mi],  bq[0], acc);
    acc = mfma16(afp2[mi], bq[1], acc);
    #pragma unroll
    for (int rr = 0; rr < 4; ++rr)
      sc[(n0 + q*4 + rr)*17 + m16] = acc[rr];
  }
  __syncthreads();

  {
    int r = tid;
    float a8[8];
    float mx = -1e30f;
    #pragma unroll
    for (int j = 0; j < 8; ++j){ a8[j] = sc[r*17 + j]; mx = fmaxf(mx, a8[j]); }
    float ssum = 0.f;
    #pragma unroll
    for (int j = 0; j < 8; ++j){ a8[j] = expf(a8[j] - mx); ssum += a8[j]; }
    float inv = 1.f/ssum;
    #pragma unroll
    for (int j = 0; j < 8; ++j)
      aT[j*264 + r] = f2b(a8[j]*inv + 1e-8f);
  }
  __syncthreads();

  {  // S tile-partials: rsum16 + one xor16 (reduce over 32 lanes)
    int j = tid >> 5, c = tid & 31;
    float p = 0.f;
    #pragma unroll
    for (int i = 0; i < 8; ++i) p += b2f(aT[j*264 + c + 32*i]);
    p = rsum16(p);
    p += __shfl_xor(p, 16);
    if ((tid & 31) == 0) Sp_out[(b*16 + tile)*8 + j] = p;
  }

  {  // U tile-partials: wave w handles h-tile nt = w; vt already in vtp regs
    f32x4 acc = {0.f, 0.f, 0.f, 0.f};
    #pragma unroll
    for (int ks = 0; ks < 8; ++ks){
      s16x8 af = *(const s16x8*)(aT + m16*264 + ks*32 + q*8);
      acc = mfma16(af, vtp[ks], acc);
    }
    float* ub = Up_out + ((b*16 + tile)*8)*64 + w*16 + m16;
    #pragma unroll
    for (int rr = 0; rr < 4; ++rr){
      int slot2 = q*4 + rr;
      if (slot2 < 8)
        ub[slot2*64] = acc[rr];
    }
  }
}

// ---------------------------------------------------------------------------
// K4: final GRU + LN_mlp + MLP(+residual) -> outp; sums the 16 tile-partials.
// UNCHANGED from round 7.
// ---------------------------------------------------------------------------
__global__ __launch_bounds__(256) void k_gru2(
    const float* __restrict__ Up, const float* __restrict__ Sp,
    const float* __restrict__ slots,
    const float* __restrict__ wih, const float* __restrict__ whh,
    const float* __restrict__ bih, const float* __restrict__ bhh,
    const float* __restrict__ w1, const float* __restrict__ b1p,
    const float* __restrict__ w2, const float* __restrict__ b2p,
    const float* __restrict__ gmlp, const float* __restrict__ bmlp,
    float* __restrict__ outp)
{
  __shared__ unsigned short ut[16*72], ht[16*72], st[16*72], hid[16*136];
  __shared__ __align__(16) float redS[16][4];
  __shared__ __align__(16) float redQ[16][4];
  const int tid = threadIdx.x;
  const int w = tid >> 6, ln = tid & 63;
  const int m16 = ln & 15, q = ln >> 4;
  const int r0 = blockIdx.x * 16;
  const int cw = w*16 + m16;

  #pragma unroll
  for (int p = 0; p < 4; ++p){
    int row = p*4 + w;
    int g = r0 + row;
    int bb = g >> 3, sl = g & 7;
    const float* up  = Up + ((bb*16)*8 + sl)*64 + ln;
    const float* spp = Sp + (bb*16)*8 + sl;
    float usum = 0.f, ssum = 0.f;
    #pragma unroll
    for (int t = 0; t < 16; ++t){
      usum += up[t*512];
      ssum += spp[t*8];
    }
    ut[row*72 + ln] = f2b(usum / ssum);
    ht[row*72 + ln] = f2b(slots[g*64 + ln]);
  }
  __syncthreads();

  f32x4 axr = {0,0,0,0}, axz = {0,0,0,0}, axn = {0,0,0,0};
  f32x4 ahr = {0,0,0,0}, ahz = {0,0,0,0}, ahn = {0,0,0,0};
  #pragma unroll
  for (int ks = 0; ks < 2; ++ks){
    s16x8 au = *(const s16x8*)(ut + m16*72 + ks*32 + q*8);
    s16x8 ah = *(const s16x8*)(ht + m16*72 + ks*32 + q*8);
    axr = mfma16(au, ld8f(wih + (      cw)*64 + ks*32 + q*8), axr);
    axz = mfma16(au, ld8f(wih + ( 64 + cw)*64 + ks*32 + q*8), axz);
    axn = mfma16(au, ld8f(wih + (128 + cw)*64 + ks*32 + q*8), axn);
    ahr = mfma16(ah, ld8f(whh + (      cw)*64 + ks*32 + q*8), ahr);
    ahz = mfma16(ah, ld8f(whh + ( 64 + cw)*64 + ks*32 + q*8), ahz);
    ahn = mfma16(ah, ld8f(whh + (128 + cw)*64 + ks*32 + q*8), ahn);
  }
  const float bxr = bih[cw], bxz = bih[64+cw], bxn = bih[128+cw];
  const float bhr = bhh[cw], bhz = bhh[64+cw], bhn = bhh[128+cw];
  float sp[4];
  #pragma unroll
  for (int rr = 0; rr < 4; ++rr){
    float xr = axr[rr] + bxr, xz = axz[rr] + bxz, xnv = axn[rr] + bxn;
    float hr = ahr[rr] + bhr, hz = ahz[rr] + bhz, hn = ahn[rr] + bhn;
    float rg = 1.f / (1.f + expf(-(xr + hr)));
    float zg = 1.f / (1.f + expf(-(xz + hz)));
    float ng = tanhf(xnv + rg*hn);
    float hv = b2f(ht[(q*4 + rr)*72 + cw]);
    sp[rr] = (1.f - zg)*ng + zg*hv;
  }

  float s1[4], s2[4];
  #pragma unroll
  for (int rr = 0; rr < 4; ++rr){
    s1[rr] = rsum16(sp[rr]);
    s2[rr] = rsum16(sp[rr]*sp[rr]);
  }
  if (m16 == 0){
    #pragma unroll
    for (int rr = 0; rr < 4; ++rr){ redS[q*4+rr][w] = s1[rr]; redQ[q*4+rr][w] = s2[rr]; }
  }
  __syncthreads();
  float sl_[4];
  {
    const float gm = gmlp[cw], bm = bmlp[cw];
    #pragma unroll
    for (int rr = 0; rr < 4; ++rr){
      f32x4 aS = *(const f32x4*)redS[q*4+rr];
      f32x4 aQ = *(const f32x4*)redQ[q*4+rr];
      float tS = aS[0]+aS[1]+aS[2]+aS[3];
      float tQ = aQ[0]+aQ[1]+aQ[2]+aQ[3];
      float mean = tS*(1.f/64.f);
      float var  = tQ*(1.f/64.f) - mean*mean;
      float rs = rsqrtf(var + 1e-5f);
      sl_[rr] = (sp[rr] - mean)*rs*gm + bm;
      st[(q*4+rr)*72 + cw] = f2b(sl_[rr]);
    }
  }
  __syncthreads();

  #pragma unroll
  for (int t2 = 0; t2 < 2; ++t2){
    int nt = w*2 + t2;
    int col = nt*16 + m16;
    f32x4 acc = {0,0,0,0};
    #pragma unroll
    for (int ks = 0; ks < 2; ++ks){
      s16x8 a = *(const s16x8*)(st + m16*72 + ks*32 + q*8);
      acc = mfma16(a, ld8f(w1 + col*64 + ks*32 + q*8), acc);
    }
    float bb = b1p[col];
    #pragma unroll
    for (int rr = 0; rr < 4; ++rr)
      hid[(q*4+rr)*136 + col] = f2b(fmaxf(acc[rr] + bb, 0.f));
  }
  __syncthreads();

  {
    f32x4 acc = {0,0,0,0};
    #pragma unroll
    for (int ks = 0; ks < 4; ++ks){
      s16x8 a = *(const s16x8*)(hid + m16*136 + ks*32 + q*8);
      acc = mfma16(a, ld8f(w2 + cw*128 + ks*32 + q*8), acc);
    }
    float bb = b2p[cw];
    #pragma unroll
    for (int rr = 0; rr < 4; ++rr){
      int row = r0 + q*4 + rr;
      outp[row*64 + cw] = sl_[rr] + acc[rr] + bb;
    }
  }
}

// ---------------------------------------------------------------------------
extern "C" void kernel_launch(void* const* d_in, const int* in_sizes, int n_in,
                              void* d_out, int out_size, void* d_ws, size_t ws_size,
                              hipStream_t stream)
{
  const float* x    = (const float*)d_in[0];
  const float* noise= (const float*)d_in[1];
  const float* Wq   = (const float*)d_in[2];
  const float* Wk   = (const float*)d_in[3];
  const float* Wv   = (const float*)d_in[4];
  const float* ling = (const float*)d_in[5];
  const float* linb = (const float*)d_in[6];
  const float* gsl  = (const float*)d_in[7];
  const float* bsl  = (const float*)d_in[8];
  const float* gmlp = (const float*)d_in[9];
  const float* bmlp = (const float*)d_in[10];
  const float* wih  = (const float*)d_in[11];
  const float* whh  = (const float*)d_in[12];
  const float* bih  = (const float*)d_in[13];
  const float* bhh  = (const float*)d_in[14];
  const float* w1   = (const float*)d_in[15];
  const float* b1p  = (const float*)d_in[16];
  const float* w2   = (const float*)d_in[17];
  const float* b2p  = (const float*)d_in[18];
  const float* mu   = (const float*)d_in[19];
  const float* lsg  = (const float*)d_in[20];

  char* ws = (char*)d_ws;
  unsigned short* kg   = (unsigned short*)(ws);              // 16 MiB
  unsigned short* vt   = (unsigned short*)(ws + 16777216);   // 16 MiB
  char* base = ws + 33554432;
  unsigned short* qws  = (unsigned short*)(base);            // 64 KiB
  float* slotsA        = (float*)(base + 65536);             // 64 KiB
  float* slotsB        = (float*)(base + 131072);
  float* slotsC        = (float*)(base + 196608);
  float* UA            = (float*)(base + 262144);            // 1 MiB partials
  float* UB            = (float*)(base + 1310720);           // 1 MiB
  float* SA            = (float*)(base + 2359296);           // 16 KiB
  float* SB            = (float*)(base + 2375680);           // 16 KiB
  unsigned short* wkb  = (unsigned short*)(base + 2392064);  // 16 KiB
  unsigned short* wvb  = (unsigned short*)(base + 2408448);  // 16 KiB
  unsigned short* wall = (unsigned short*)(base + 2424832);  // 88 KiB packed weights
  float* outp          = (float*)d_out;

  hipLaunchKernelGGL(k_wpack, dim3(60), dim3(256), 0, stream,
                     Wk, Wv, wih, whh, w1, w2, Wq, wkb, wvb, wall);
  hipLaunchKernelGGL(k_lnkv7, dim3(1040), dim3(256), 0, stream,
                     x, wkb, wvb, ling, linb, kg, vt,
                     noise, mu, lsg, gsl, bsl, Wq, slotsA, qws);
  // it=0: q from qws; write iter-0 partials into UA/SA
  hipLaunchKernelGGL(k_attn3, dim3(512), dim3(256), 0, stream,
                     kg, vt, qws, wall, bih, bhh, b1p, b2p, gmlp, bmlp, gsl, bsl,
                     UA, SA, UA, SA, slotsA, slotsA, 0);
  // it=1: gru(sum UA/SA, slotsA)->slotsB + q; write iter-1 partials into UB/SB
  hipLaunchKernelGGL(k_attn3, dim3(512), dim3(256), 0, stream,
                     kg, vt, qws, wall, bih, bhh, b1p, b2p, gmlp, bmlp, gsl, bsl,
                     UA, SA, UB, SB, slotsA, slotsB, 1);
  // it=2: gru(sum UB/SB, slotsB)->slotsC + q; write iter-2 partials into UA/SA
  hipLaunchKernelGGL(k_attn3, dim3(512), dim3(256), 0, stream,
                     kg, vt, qws, wall, bih, bhh, b1p, b2p, gmlp, bmlp, gsl, bsl,
                     UB, SB, UA, SA, slotsB, slotsC, 2);
  // final gru(sum UA/SA, slotsC) -> outp
  hipLaunchKernelGGL(k_gru2, dim3(16), dim3(256), 0, stream, UA, SA, slotsC,
                     wih, whh, bih, bhh, w1, b1p, w2, b2p, gmlp, bmlp, outp);
  (void)in_sizes; (void)n_in; (void)out_size; (void)ws_size;
}